// Round 9
// baseline (779.017 us; speedup 1.0000x reference)
//
#include <hip/hip_runtime.h>

typedef unsigned short u16;
typedef unsigned int u32;
typedef unsigned long long u64;
typedef signed char s8;
typedef __attribute__((ext_vector_type(8))) short bfrag8;
typedef __attribute__((ext_vector_type(4))) float f32x4;
typedef __attribute__((ext_vector_type(4))) int i32x4;
typedef __attribute__((address_space(1))) const void gconst_void;
typedef __attribute__((address_space(3))) void lds_void_t;

// ---------- helpers ----------
__device__ __forceinline__ float bf2f(u16 u) {
  return __uint_as_float(((u32)u) << 16);
}
__device__ __forceinline__ u16 f2bf(float f) {
  u32 u = __float_as_uint(f);
  u32 r = (u + 0x7FFFu + ((u >> 16) & 1u)) >> 16;  // RTNE
  return (u16)r;
}
__device__ __forceinline__ void split3(float v, u16& hi, u16& mi, u16& lo) {
  hi = f2bf(v); float r1 = v - bf2f(hi);
  mi = f2bf(r1); float r2 = r1 - bf2f(mi);
  lo = f2bf(r2);
}
__device__ __forceinline__ float ld1(const void* p, int isbf, long idx) {
  return isbf ? bf2f(((const u16*)p)[idx]) : ((const float*)p)[idx];
}
__device__ __forceinline__ void ld4(const void* p, int isbf, long base, long gc, long bound, float v[4]) {
  if (gc + 3 < bound && ((base & 3) == 0)) {
    if (isbf) {
      const ushort4 u = *(const ushort4*)((const u16*)p + base);
      v[0] = bf2f(u.x); v[1] = bf2f(u.y); v[2] = bf2f(u.z); v[3] = bf2f(u.w);
    } else {
      const float4 f = *(const float4*)((const float*)p + base);
      v[0] = f.x; v[1] = f.y; v[2] = f.z; v[3] = f.w;
    }
  } else {
    #pragma unroll
    for (int d = 0; d < 4; ++d) v[d] = (gc + d < bound) ? ld1(p, isbf, base + d) : 0.f;
  }
}

// ---------- input dtype autodetect (uint4 vectorized) ----------
__global__ void detect_k(const u32* __restrict__ a, long nw, int* __restrict__ flag) {
  long nv = nw >> 2;
  long stride = (long)gridDim.x * 256;
  int f = 0;
  for (long j = (long)blockIdx.x * 256 + threadIdx.x; j < nv; j += stride) {
    uint4 w = ((const uint4*)a)[j];
    if (w.x == 0x00003F80u || w.x == 0x3F803F80u ||
        w.y == 0x00003F80u || w.y == 0x3F803F80u ||
        w.z == 0x00003F80u || w.z == 0x3F803F80u ||
        w.w == 0x00003F80u || w.w == 0x3F803F80u) f = 1;
  }
  if (__any(f)) {
    if ((threadIdx.x & 63) == 0) atomicOr(flag, 1);
  }
}

__device__ __forceinline__ int get_bf(int abf, const int* dtf) {
  return (abf >= 0) ? abf : *dtf;
}

// ---------- async global->LDS stage ----------
__device__ __forceinline__ void stageB16(const void* g, void* lds) {
#if __has_builtin(__builtin_amdgcn_global_load_lds)
  __builtin_amdgcn_global_load_lds((gconst_void*)g, (lds_void_t*)lds, 16, 0, 0);
#else
  int lane = threadIdx.x & 63;
  *(int4*)((char*)lds + lane * 16) = *(const int4*)g;
#endif
}

// ---------- i8 triangle SYRK, single-pass, 8 waves, BK=128 (32 barriers):
// dbuf pipeline + direct bf16 write + LDS-transpose mirror + exact f64 row sums.
// Integer-exact => output remap / K-suborder is bit-identical.
__global__ __launch_bounds__(512) void syrk_tri_i8_full(
    const s8* __restrict__ Ag, int ldk, int K, int ldc,
    u16* __restrict__ Ah, u16* __restrict__ Al, double* __restrict__ rsum)
{
  __shared__ s8 At[2][128 * 128];
  __shared__ s8 Bt[2][128 * 128];
  __shared__ int tb[8][16][17];
  const int t = blockIdx.x;
  int ti = (int)((sqrtf((float)(8 * t + 1)) - 1.0f) * 0.5f);
  while ((ti + 1) * (ti + 2) / 2 <= t) ++ti;
  while (ti * (ti + 1) / 2 > t) --ti;
  const int tj = t - ti * (ti + 1) / 2;

  const int tid = threadIdx.x;
  const int wave = tid >> 6, lane = tid & 63;
  const int wr = wave >> 1;   // 0..3: rows wr*32 .. wr*32+31
  const int wc = wave & 1;    // 0..1: cols wc*64 .. wc*64+63
  const long rowA0 = (long)ti * 128;
  const long rowB0 = (long)tj * 128;
  const int nsteps = K / 128;

  i32x4 acc[2][4];
  #pragma unroll
  for (int i = 0; i < 2; ++i)
    #pragma unroll
    for (int j = 0; j < 4; ++j) acc[i][j] = (i32x4)0;

  const int srow2 = lane >> 3;           // 0..7 (8 rows per stage call)
  const int scol2 = (lane & 7) * 16;     // 0..112, 16B each -> 128B row
  const int m = lane & 15, q = lane >> 4;

  auto stage = [&](int buf, int k0) {
    #pragma unroll
    for (int tt = 0; tt < 2; ++tt) {
      const int r = wave * 16 + tt * 8;
      stageB16(Ag + (rowA0 + r + srow2) * (long)ldk + k0 + scol2, At[buf] + r * 128);
      stageB16(Ag + (rowB0 + r + srow2) * (long)ldk + k0 + scol2, Bt[buf] + r * 128);
    }
  };

  stage(0, 0);
  __syncthreads();
  int cur = 0;
  for (int st = 0; st < nsteps; ++st) {
    if (st + 1 < nsteps) stage(cur ^ 1, (st + 1) * 128);

    #pragma unroll
    for (int sub = 0; sub < 2; ++sub) {
      i32x4 af[2], bf[4];
      #pragma unroll
      for (int mt = 0; mt < 2; ++mt)
        af[mt] = *(const i32x4*)(At[cur] + (wr * 32 + mt * 16 + m) * 128 + sub * 64 + q * 16);
      #pragma unroll
      for (int nt = 0; nt < 4; ++nt)
        bf[nt] = *(const i32x4*)(Bt[cur] + (wc * 64 + nt * 16 + m) * 128 + sub * 64 + q * 16);
      #pragma unroll
      for (int mt = 0; mt < 2; ++mt)
        #pragma unroll
        for (int nt = 0; nt < 4; ++nt)
          acc[mt][nt] = __builtin_amdgcn_mfma_i32_16x16x64_i8(af[mt], bf[nt], acc[mt][nt], 0, 0, 0);
    }
    if (st + 1 < nsteps) __syncthreads();
    cur ^= 1;
  }

  // epilogue: direct write + exact row sums (f64 atomics; integer-exact)
  #pragma unroll
  for (int mt = 0; mt < 2; ++mt) {
    double rp[4] = {0.0, 0.0, 0.0, 0.0};
    #pragma unroll
    for (int nt = 0; nt < 4; ++nt) {
      const long gr0 = rowA0 + wr * 32 + mt * 16 + q * 4;
      const long gc = rowB0 + wc * 64 + nt * 16 + m;
      #pragma unroll
      for (int r = 0; r < 4; ++r) {
        const long gr = gr0 + r;
        int iv = (gr == gc) ? 0 : acc[mt][nt][r];
        float fv = (float)iv;
        long idx = gr * ldc + gc;
        u16 h = f2bf(fv);
        Ah[idx] = h;
        if (Al) Al[idx] = f2bf(fv - bf2f(h));
        rp[r] += (double)iv;
      }
    }
    #pragma unroll
    for (int r = 0; r < 4; ++r) {
      double v = rp[r];
      for (int off = 8; off > 0; off >>= 1) v += __shfl_down(v, off);
      if (m == 0) atomicAdd(&rsum[rowA0 + wr * 32 + mt * 16 + q * 4 + r], v);
    }
  }
  if (ti != tj) {
    #pragma unroll
    for (int nt = 0; nt < 4; ++nt) {
      double cp = 0.0;
      #pragma unroll
      for (int mt = 0; mt < 2; ++mt) {
        #pragma unroll
        for (int r = 0; r < 4; ++r) tb[wave][q * 4 + r][m] = acc[mt][nt][r];
        const long baseR = rowB0 + wc * 64 + nt * 16;
        const long baseC = rowA0 + wr * 32 + mt * 16;
        #pragma unroll
        for (int r = 0; r < 4; ++r) {
          float tv = (float)tb[wave][m][q * 4 + r];
          long idx = (baseR + q * 4 + r) * ldc + baseC + m;
          u16 h = f2bf(tv);
          Ah[idx] = h;
          if (Al) Al[idx] = f2bf(tv - bf2f(h));
        }
        #pragma unroll
        for (int r = 0; r < 4; ++r) cp += (double)acc[mt][nt][r];
      }
      double v = cp;
      v += __shfl_down(v, 32);
      v += __shfl_down(v, 16);
      if (q == 0) atomicAdd(&rsum[rowB0 + wc * 64 + nt * 16 + m], v);
    }
  }
}

// ---------- i8 triangle SYRK, K-split -> PT parts (exact partials) ----------
template<typename PT>
__global__ __launch_bounds__(256) void syrk_tri_i8_parts(
    const s8* __restrict__ Ag, int ldk, int Ksplit, int ntri,
    PT* __restrict__ parts)
{
  __shared__ s8 At[2][128 * 64];
  __shared__ s8 Bt[2][128 * 64];
  const int t = blockIdx.x;
  int ti = (int)((sqrtf((float)(8 * t + 1)) - 1.0f) * 0.5f);
  while ((ti + 1) * (ti + 2) / 2 <= t) ++ti;
  while (ti * (ti + 1) / 2 > t) --ti;
  const int tj = t - ti * (ti + 1) / 2;

  const int tid = threadIdx.x;
  const int wave = tid >> 6, lane = tid & 63;
  const int wr = wave >> 1, wc = wave & 1;
  const long rowA0 = (long)ti * 128;
  const long rowB0 = (long)tj * 128;
  const int kbeg = blockIdx.y * Ksplit;
  const int nsteps = Ksplit / 64;

  i32x4 acc[4][4];
  #pragma unroll
  for (int i = 0; i < 4; ++i)
    #pragma unroll
    for (int j = 0; j < 4; ++j) acc[i][j] = (i32x4)0;

  const int srow = lane >> 2;
  const int scol = (lane & 3) * 16;
  const int m = lane & 15, q = lane >> 4;

  auto stage = [&](int buf, int k0) {
    #pragma unroll
    for (int tt = 0; tt < 2; ++tt) {
      const int r = wave * 32 + tt * 16;
      stageB16(Ag + (rowA0 + r + srow) * (long)ldk + k0 + scol, At[buf] + r * 64);
      stageB16(Ag + (rowB0 + r + srow) * (long)ldk + k0 + scol, Bt[buf] + r * 64);
    }
  };

  stage(0, kbeg);
  __syncthreads();
  int cur = 0;
  for (int st = 0; st < nsteps; ++st) {
    if (st + 1 < nsteps) stage(cur ^ 1, kbeg + (st + 1) * 64);

    i32x4 af[4], bf[4];
    #pragma unroll
    for (int mt = 0; mt < 4; ++mt)
      af[mt] = *(const i32x4*)(At[cur] + (wr * 64 + mt * 16 + m) * 64 + q * 16);
    #pragma unroll
    for (int nt = 0; nt < 4; ++nt)
      bf[nt] = *(const i32x4*)(Bt[cur] + (wc * 64 + nt * 16 + m) * 64 + q * 16);
    #pragma unroll
    for (int mt = 0; mt < 4; ++mt)
      #pragma unroll
      for (int nt = 0; nt < 4; ++nt)
        acc[mt][nt] = __builtin_amdgcn_mfma_i32_16x16x64_i8(af[mt], bf[nt], acc[mt][nt], 0, 0, 0);
    if (st + 1 < nsteps) __syncthreads();
    cur ^= 1;
  }

  PT* P = parts + ((long)blockIdx.y * ntri + t) * 16384;
  #pragma unroll
  for (int mt = 0; mt < 4; ++mt) {
    #pragma unroll
    for (int nt = 0; nt < 4; ++nt) {
      const int r0 = wr * 64 + mt * 16 + q * 4;
      const int c = wc * 64 + nt * 16 + m;
      #pragma unroll
      for (int r = 0; r < 4; ++r)
        P[(r0 + r) * 128 + c] = (PT)acc[mt][nt][r];
    }
  }
}

// Sum PT parts per tile, zero diag, emit bf16 hi(/lo) planes + coalesced mirror
// via padded LDS transpose; fused EXACT row sums (double atomics on rs).
template<typename PT>
__global__ __launch_bounds__(256) void reduce_tri_i8_k(
    const PT* __restrict__ parts, int ntri, int n, int nz,
    u16* __restrict__ Ah, u16* __restrict__ Al, double* __restrict__ rs)
{
  __shared__ float T[128 * 33];
  const int t = blockIdx.x >> 2;
  const int slab = blockIdx.x & 3;
  int ti = (int)((sqrtf((float)(8 * t + 1)) - 1.0f) * 0.5f);
  while ((ti + 1) * (ti + 2) / 2 <= t) ++ti;
  while (ti * (ti + 1) / 2 > t) --ti;
  const int tj = t - ti * (ti + 1) / 2;
  const long rowA0 = (long)ti * 128;
  const long rowB0 = (long)tj * 128;
  const int r0 = slab * 32;
  const int tid = threadIdx.x;
  const int lane = tid & 63;
  const long tstride = (long)ntri * 16384;

  #pragma unroll
  for (int it = 0; it < 16; ++it) {
    const int idx = it * 256 + tid;       // 0..4095 covers 32x128 slab
    const int lr = idx >> 7;              // local row in slab
    const int lc = idx & 127;             // local col
    long base = (long)t * 16384 + (r0 + lr) * 128 + lc;
    int v = 0;
    for (int z = 0; z < nz; ++z) v += (int)parts[(long)z * tstride + base];
    const long gr = rowA0 + r0 + lr;
    const long gc = rowB0 + lc;
    if (gr == gc) v = 0;
    const float fv = (float)v;
    const u16 h = f2bf(fv);
    const long o = gr * n + gc;
    Ah[o] = h;
    if (Al) Al[o] = f2bf(fv - bf2f(h));
    T[lc * 33 + lr] = fv;                 // transposed store, stride-33: conflict-free
    // exact row-sum partial: all 64 lanes of this wave share row gr
    float wsum = fv;
    #pragma unroll
    for (int off = 32; off > 0; off >>= 1) wsum += __shfl_down(wsum, off);
    if (lane == 0) atomicAdd(&rs[gr], (double)wsum);
  }
  if (ti == tj) return;                   // diag tile fully covers its own block
  __syncthreads();
  #pragma unroll
  for (int it = 0; it < 16; ++it) {
    const int idx = it * 256 + tid;       // covers 128x32 mirror slab
    const int mr = idx >> 5;              // 0..127 mirror row
    const int mc = idx & 31;              // 0..31 mirror col
    const float fv = T[mr * 33 + mc];     // = L[r0+mc][mr]
    const u16 h = f2bf(fv);
    const long o = (rowB0 + mr) * n + rowA0 + r0 + mc;
    Ah[o] = h;
    if (Al) Al[o] = f2bf(fv - bf2f(h));
    // mirror row-sum: 32-lane groups share row (rowB0+mr); lanes 0 and 32 emit
    float ws = fv;
    #pragma unroll
    for (int off = 16; off > 0; off >>= 1) ws += __shfl_down(ws, off);
    if ((lane & 31) == 0) atomicAdd(&rs[rowB0 + mr], (double)ws);
  }
}

// ---------- bf16 2-plane triangle SYRK, K-split parts; double-buffered ----------
__global__ __launch_bounds__(256) void syrk_tri2_parts(
    const u16* __restrict__ Ah, const u16* __restrict__ Al, int ldk,
    float* __restrict__ parts, int n, int per)
{
  __shared__ u16 Ath[2][128 * 32];
  __shared__ u16 Bth[2][128 * 32];
  __shared__ u16 Atl[2][128 * 32];
  __shared__ u16 Btl[2][128 * 32];
  const int t = blockIdx.x;
  int ti = (int)((sqrtf((float)(8 * t + 1)) - 1.0f) * 0.5f);
  while ((ti + 1) * (ti + 2) / 2 <= t) ++ti;
  while (ti * (ti + 1) / 2 > t) --ti;
  const int tj = t - ti * (ti + 1) / 2;

  const int tid = threadIdx.x;
  const int wave = tid >> 6, lane = tid & 63;
  const int wr = wave >> 1, wc = wave & 1;
  const long rowA0 = (long)ti * 128;
  const long rowB0 = (long)tj * 128;
  const int kbeg = blockIdx.y * per;
  const int nsteps = per / 32;

  f32x4 acc[4][4];
  #pragma unroll
  for (int i = 0; i < 4; ++i)
    #pragma unroll
    for (int j = 0; j < 4; ++j) acc[i][j] = (f32x4)0.f;

  const int srow = lane >> 2;
  const int scol = (lane & 3) * 8;
  const int m = lane & 15, q = lane >> 4;

  auto stage = [&](int buf, int k0) {
    #pragma unroll
    for (int tt = 0; tt < 2; ++tt) {
      const int r = wave * 32 + tt * 16;
      stageB16(Ah + (rowA0 + r + srow) * (long)ldk + k0 + scol, Ath[buf] + r * 32);
      stageB16(Ah + (rowB0 + r + srow) * (long)ldk + k0 + scol, Bth[buf] + r * 32);
      stageB16(Al + (rowA0 + r + srow) * (long)ldk + k0 + scol, Atl[buf] + r * 32);
      stageB16(Al + (rowB0 + r + srow) * (long)ldk + k0 + scol, Btl[buf] + r * 32);
    }
  };

  stage(0, kbeg);
  __syncthreads();
  int cur = 0;
  for (int st = 0; st < nsteps; ++st) {
    if (st + 1 < nsteps) stage(cur ^ 1, kbeg + (st + 1) * 32);

    bfrag8 afh[4], afl[4], bfh[4], bfl[4];
    #pragma unroll
    for (int mt = 0; mt < 4; ++mt) {
      afh[mt] = *(const bfrag8*)(Ath[cur] + (wr * 64 + mt * 16 + m) * 32 + q * 8);
      afl[mt] = *(const bfrag8*)(Atl[cur] + (wr * 64 + mt * 16 + m) * 32 + q * 8);
    }
    #pragma unroll
    for (int nt = 0; nt < 4; ++nt) {
      bfh[nt] = *(const bfrag8*)(Bth[cur] + (wc * 64 + nt * 16 + m) * 32 + q * 8);
      bfl[nt] = *(const bfrag8*)(Btl[cur] + (wc * 64 + nt * 16 + m) * 32 + q * 8);
    }
    #pragma unroll
    for (int mt = 0; mt < 4; ++mt)
      #pragma unroll
      for (int nt = 0; nt < 4; ++nt) {
        acc[mt][nt] = __builtin_amdgcn_mfma_f32_16x16x32_bf16(afh[mt], bfh[nt], acc[mt][nt], 0, 0, 0);
        acc[mt][nt] = __builtin_amdgcn_mfma_f32_16x16x32_bf16(afh[mt], bfl[nt], acc[mt][nt], 0, 0, 0);
        acc[mt][nt] = __builtin_amdgcn_mfma_f32_16x16x32_bf16(afl[mt], bfh[nt], acc[mt][nt], 0, 0, 0);
        acc[mt][nt] = __builtin_amdgcn_mfma_f32_16x16x32_bf16(afl[mt], bfl[nt], acc[mt][nt], 0, 0, 0);
      }
    if (st + 1 < nsteps) __syncthreads();
    cur ^= 1;
  }

  float* P = parts + (long)blockIdx.y * n * n;
  #pragma unroll
  for (int mt = 0; mt < 4; ++mt) {
    #pragma unroll
    for (int nt = 0; nt < 4; ++nt) {
      const long gr0 = rowA0 + wr * 64 + mt * 16 + q * 4;
      const long gc = rowB0 + wc * 64 + nt * 16 + m;
      #pragma unroll
      for (int r = 0; r < 4; ++r)
        P[(gr0 + r) * n + gc] = acc[mt][nt][r];
    }
  }
}

// sum nz parts, mirror, zero diag; Ah/Al write + f64 row sums.
__global__ void reduce_tri_mirror_k(const float* __restrict__ parts,
                                    u16* __restrict__ Ah, u16* __restrict__ Al,
                                    double* __restrict__ rsum, int n, int nz) {
  __shared__ double red[256];
  const int tid = threadIdx.x;
  long idx = (long)blockIdx.x * 256 + tid;
  long nn = (long)n * n;
  long r = idx / n, c = idx - r * n;
  double myv = 0.0;
  if (idx < nn) {
    if (r == c) {
      Ah[idx] = 0; Al[idx] = 0;
    } else if (r > c) {
      float s = 0.f;
      for (int z = 0; z < nz; ++z) s += parts[(long)z * nn + r * n + c];
      long mi = c * n + r;
      u16 h = f2bf(s);
      u16 l = f2bf(s - bf2f(h));
      Ah[idx] = h; Al[idx] = l;
      Ah[mi] = h;  Al[mi] = l;
      myv = (double)s;
      atomicAdd(&rsum[c], (double)s);
    }
  }
  red[tid] = myv;
  __syncthreads();
  for (int st = 128; st > 0; st >>= 1) {
    if (tid < st) red[tid] += red[tid + st];
    __syncthreads();
  }
  if (tid == 0 && idx < nn) atomicAdd(&rsum[r], red[0]);
}

// ---------- fused build (i8 augment operand) + gather-x, 4-wide vectorized ----------
__global__ void bg_i8_k(const void* __restrict__ src, int srcbf, int nsrc,
                        const int* __restrict__ perm, int kRows,
                        s8* __restrict__ Ag, const int* __restrict__ dtf,
                        const float* __restrict__ xsrc, const float* __restrict__ score,
                        float* __restrict__ xdst, unsigned nbB) {
  if (blockIdx.x < nbB) {
    long tot4 = ((long)kRows * nsrc) >> 2;
    long i4 = (long)blockIdx.x * 256 + threadIdx.x;
    if (i4 >= tot4) return;
    long idx = i4 << 2;
    int r = (int)(idx / nsrc);
    int c = (int)(idx - (long)r * nsrc);
    int p = perm[r];
    float v[4];
    if (get_bf(srcbf, dtf)) {
      ushort4 u = *(const ushort4*)((const u16*)src + (long)p * nsrc + c);
      v[0] = bf2f(u.x); v[1] = bf2f(u.y); v[2] = bf2f(u.z); v[3] = bf2f(u.w);
    } else {
      float4 f = *(const float4*)((const float*)src + (long)p * nsrc + c);
      v[0] = f.x; v[1] = f.y; v[2] = f.z; v[3] = f.w;
    }
    char4 o;
    o.x = (s8)(int)(v[0] + ((c + 0 == p) ? 1.f : 0.f));
    o.y = (s8)(int)(v[1] + ((c + 1 == p) ? 1.f : 0.f));
    o.z = (s8)(int)(v[2] + ((c + 2 == p) ? 1.f : 0.f));
    o.w = (s8)(int)(v[3] + ((c + 3 == p) ? 1.f : 0.f));
    *(char4*)(Ag + idx) = o;
  } else {
    long tot4 = (long)kRows * 50;  // 200/4
    long i4 = (long)(blockIdx.x - nbB) * 256 + threadIdx.x;
    if (i4 >= tot4) return;
    long idx = i4 << 2;
    int r = (int)(idx / 200);
    int c = (int)(idx - (long)r * 200);
    int p = perm[r];
    float4 x = *(const float4*)(xsrc + (long)p * 200 + c);
    float sc = score[p];
    x.x *= sc; x.y *= sc; x.z *= sc; x.w *= sc;
    *(float4*)(xdst + idx) = x;
  }
}

// fused build (2-plane bf16 from Ah2/Al2) + gather-x, 4-wide vectorized
__global__ void bg_sp_k(const u16* __restrict__ srcH, const u16* __restrict__ srcL,
                        int nsrc, const int* __restrict__ perm, int kRows,
                        u16* __restrict__ Agh, u16* __restrict__ Agl,
                        const float* __restrict__ xsrc, const float* __restrict__ score,
                        float* __restrict__ xdst, unsigned nbB) {
  if (blockIdx.x < nbB) {
    long tot4 = ((long)kRows * nsrc) >> 2;
    long i4 = (long)blockIdx.x * 256 + threadIdx.x;
    if (i4 >= tot4) return;
    long idx = i4 << 2;
    int r = (int)(idx / nsrc);
    int c = (int)(idx - (long)r * nsrc);
    int p = perm[r];
    long si = (long)p * nsrc + c;
    ushort4 uh = *(const ushort4*)(srcH + si);
    ushort4 ul = *(const ushort4*)(srcL + si);
    ushort4 oh, ol;
    {
      float v = bf2f(uh.x) + bf2f(ul.x); if (c + 0 == p) v += 1.f;
      oh.x = f2bf(v); ol.x = f2bf(v - bf2f(oh.x));
    }
    {
      float v = bf2f(uh.y) + bf2f(ul.y); if (c + 1 == p) v += 1.f;
      oh.y = f2bf(v); ol.y = f2bf(v - bf2f(oh.y));
    }
    {
      float v = bf2f(uh.z) + bf2f(ul.z); if (c + 2 == p) v += 1.f;
      oh.z = f2bf(v); ol.z = f2bf(v - bf2f(oh.z));
    }
    {
      float v = bf2f(uh.w) + bf2f(ul.w); if (c + 3 == p) v += 1.f;
      oh.w = f2bf(v); ol.w = f2bf(v - bf2f(oh.w));
    }
    *(ushort4*)(Agh + idx) = oh;
    *(ushort4*)(Agl + idx) = ol;
  } else {
    long tot4 = (long)kRows * 50;
    long i4 = (long)(blockIdx.x - nbB) * 256 + threadIdx.x;
    if (i4 >= tot4) return;
    long idx = i4 << 2;
    int r = (int)(idx / 200);
    int c = (int)(idx - (long)r * 200);
    int p = perm[r];
    float4 x = *(const float4*)(xsrc + (long)p * 200 + c);
    float sc = score[p];
    x.x *= sc; x.y *= sc; x.z *= sc; x.w *= sc;
    *(float4*)(xdst + idx) = x;
  }
}

// ---------- MFMA aggregation: Y = A @ Z ----------
// 8 waves (512 thr); blockIdx.z splits the 13 output col-subtiles 7/6 so LDS
// fits 2 blocks/CU; double-buffered async pipeline.
template<int HASAL>
__global__ __launch_bounds__(512, 4) void agg_mfma8z(
    const u16* __restrict__ Ah, const u16* __restrict__ Al,
    const u16* __restrict__ ZT, float* __restrict__ parts,
    int K, int per_steps)
{
  __shared__ u16 At[2][8 * 512];
  __shared__ u16 Alt[HASAL ? 2 * 8 * 512 : 2];
  __shared__ u16 Zt[2][21 * 512];

  const int tid = threadIdx.x;
  const int wave = tid >> 6, lane = tid & 63;
  const int zh = blockIdx.z;
  const int ct0 = zh ? 7 : 0;                  // global subtile base
  const int nts = zh ? 6 : 7;                  // subtiles this block
  const int cth = (nts + 1) >> 1;              // per-col-half split (4/3 or 3/3)
  const int rg = wave & 3;                     // row group: rows rg*32..rg*32+31
  const int cg = wave >> 2;                    // col half within block
  const int wct0 = cg ? cth : 0;
  const int wnct = cg ? (nts - cth) : cth;
  const long row0 = (long)blockIdx.x * 128;
  const int chunk = blockIdx.y;
  const int kbeg = chunk * per_steps * 32;
  const int nsteps = (min(K, kbeg + per_steps * 32) - kbeg) / 32;
  const int m = lane & 15, q = lane >> 4;
  const int srow = lane >> 2, scol = (lane & 3) * 8;
  const int nstg = (HASAL ? 16 : 8) + 3 * nts;

  auto stage = [&](int buf, int k0) {
    for (int s = wave; s < nstg; s += 8) {
      if (s < 8) {
        stageB16(Ah + (row0 + s * 16 + srow) * (long)K + k0 + scol, At[buf] + s * 512);
      } else if (HASAL && s < 16) {
        stageB16(Al + (row0 + (s - 8) * 16 + srow) * (long)K + k0 + scol,
                 (u16*)Alt + (buf * 8 + (s - 8)) * 512);
      } else {
        const int zz = s - (HASAL ? 16 : 8);
        const int pl = (zz >= 2 * nts) ? 2 : ((zz >= nts) ? 1 : 0);
        const int c = zz - pl * nts;
        stageB16(ZT + ((long)(pl * 208 + (ct0 + c) * 16 + srow)) * K + k0 + scol,
                 Zt[buf] + (pl * 7 + c) * 512);
      }
    }
  };

  f32x4 acc[2][4];
  #pragma unroll
  for (int rt = 0; rt < 2; ++rt)
    #pragma unroll
    for (int ct = 0; ct < 4; ++ct) acc[rt][ct] = (f32x4)0.f;

  stage(0, kbeg);
  __syncthreads();
  int cur = 0;
  for (int t = 0; t < nsteps; ++t) {
    if (t + 1 < nsteps) stage(cur ^ 1, kbeg + (t + 1) * 32);  // async prefetch

    const u16* Atb = At[cur];
    const u16* Ztb = Zt[cur];
    bfrag8 af0 = *(const bfrag8*)(Atb + (rg * 2) * 512 + m * 32 + q * 8);
    bfrag8 af1 = *(const bfrag8*)(Atb + (rg * 2 + 1) * 512 + m * 32 + q * 8);
    bfrag8 al0, al1;
    if (HASAL) {
      const u16* Altb = (const u16*)Alt + cur * 8 * 512;
      al0 = *(const bfrag8*)(Altb + (rg * 2) * 512 + m * 32 + q * 8);
      al1 = *(const bfrag8*)(Altb + (rg * 2 + 1) * 512 + m * 32 + q * 8);
    }
    #pragma unroll
    for (int ct = 0; ct < 4; ++ct) {
      if (ct < wnct) {
        const int gct = wct0 + ct;
        bfrag8 b0 = *(const bfrag8*)(Ztb + (0 * 7 + gct) * 512 + m * 32 + q * 8);
        bfrag8 b1 = *(const bfrag8*)(Ztb + (1 * 7 + gct) * 512 + m * 32 + q * 8);
        bfrag8 b2 = *(const bfrag8*)(Ztb + (2 * 7 + gct) * 512 + m * 32 + q * 8);
        acc[0][ct] = __builtin_amdgcn_mfma_f32_16x16x32_bf16(af0, b0, acc[0][ct], 0, 0, 0);
        acc[0][ct] = __builtin_amdgcn_mfma_f32_16x16x32_bf16(af0, b1, acc[0][ct], 0, 0, 0);
        acc[0][ct] = __builtin_amdgcn_mfma_f32_16x16x32_bf16(af0, b2, acc[0][ct], 0, 0, 0);
        acc[1][ct] = __builtin_amdgcn_mfma_f32_16x16x32_bf16(af1, b0, acc[1][ct], 0, 0, 0);
        acc[1][ct] = __builtin_amdgcn_mfma_f32_16x16x32_bf16(af1, b1, acc[1][ct], 0, 0, 0);
        acc[1][ct] = __builtin_amdgcn_mfma_f32_16x16x32_bf16(af1, b2, acc[1][ct], 0, 0, 0);
        if (HASAL) {
          acc[0][ct] = __builtin_amdgcn_mfma_f32_16x16x32_bf16(al0, b0, acc[0][ct], 0, 0, 0);
          acc[0][ct] = __builtin_amdgcn_mfma_f32_16x16x32_bf16(al0, b1, acc[0][ct], 0, 0, 0);
          acc[1][ct] = __builtin_amdgcn_mfma_f32_16x16x32_bf16(al1, b0, acc[1][ct], 0, 0, 0);
          acc[1][ct] = __builtin_amdgcn_mfma_f32_16x16x32_bf16(al1, b1, acc[1][ct], 0, 0, 0);
        }
      }
    }
    if (t + 1 < nsteps) __syncthreads();        // vmcnt(0): prefetch landed; reads done
    cur ^= 1;
  }

  float* P = parts + (long)chunk * gridDim.x * 128 * 208;
  #pragma unroll
  for (int rt = 0; rt < 2; ++rt) {
    #pragma unroll
    for (int ct = 0; ct < 4; ++ct) {
      if (ct < wnct) {
        const long grow0 = row0 + rg * 32 + rt * 16 + q * 4;
        const long gcol = (ct0 + wct0 + ct) * 16 + m;
        #pragma unroll
        for (int r = 0; r < 4; ++r)
          P[(grow0 + r) * 208 + gcol] = acc[rt][ct][r];
      }
    }
  }
}

// fused: reduce parts + GCN epilogue (+ optional pooling score)
__global__ __launch_bounds__(256) void reduce_epi_k(
    const float* __restrict__ parts, const float* __restrict__ Zs,
    const double* __restrict__ rs, const float* __restrict__ b,
    float* __restrict__ out, int n, int nz, int relu,
    const float* __restrict__ pw, float* __restrict__ score)
{
  __shared__ float vrow[200];
  const int i = blockIdx.x, tid = threadIdx.x;
  float dv = (float)(1.0 / sqrt(rs[i] + 2.0));
  if (tid < 200) {
    long base = (long)i * 208 + tid;
    float s = 0.f;
    for (int c = 0; c < nz; ++c) s += parts[(long)c * n * 208 + base];
    float v = dv * (s + 2.f * Zs[(long)i * 200 + tid]) + b[tid];
    if (relu) v = fmaxf(v, 0.f);
    out[(long)i * 200 + tid] = v;
    if (score) vrow[tid] = v;
  }
  if (!score) return;
  __syncthreads();
  if (tid < 64) {
    double ps = 0.0;
    for (int j = tid; j < 200; j += 64) { double w = pw[j]; ps += w * w; }
    for (int off = 32; off > 0; off >>= 1) ps += __shfl_down(ps, off);
    double nrm = sqrt(__shfl(ps, 0));
    double s = 0.0;
    for (int j = tid; j < 200; j += 64) s += (double)vrow[j] * (double)pw[j];
    for (int off = 32; off > 0; off >>= 1) s += __shfl_down(s, off);
    if (tid == 0) score[i] = (float)tanh(s / nrm);
  }
}

// fused adj->bf16 plane + row sums (level 0), vectorized.
__global__ void a_from_adj_rs_k(const void* __restrict__ adj, const int* __restrict__ dtf,
                                int n, u16* __restrict__ Ah, double* __restrict__ rs) {
  __shared__ double red[256];
  int bf = *dtf;
  const int row = blockIdx.x, tid = threadIdx.x;
  const long base = (long)row * n;
  double s = 0.0;
  if (bf) {
    const uint4* src = (const uint4*)((const u16*)adj + base);
    uint4* dst = (uint4*)(Ah + base);
    for (int j = tid; j < (n >> 3); j += 256) {
      uint4 v = src[j];
      dst[j] = v;
      s += (double)(bf2f((u16)(v.x & 0xFFFFu)) + bf2f((u16)(v.x >> 16))
                  + bf2f((u16)(v.y & 0xFFFFu)) + bf2f((u16)(v.y >> 16))
                  + bf2f((u16)(v.z & 0xFFFFu)) + bf2f((u16)(v.z >> 16))
                  + bf2f((u16)(v.w & 0xFFFFu)) + bf2f((u16)(v.w >> 16)));
    }
  } else {
    const float4* src = (const float4*)((const float*)adj + base);
    ushort4* dst = (ushort4*)(Ah + base);
    for (int j = tid; j < (n >> 2); j += 256) {
      float4 v = src[j];
      ushort4 o;
      o.x = f2bf(v.x); o.y = f2bf(v.y); o.z = f2bf(v.z); o.w = f2bf(v.w);
      dst[j] = o;
      s += (double)(v.x + v.y + v.z + v.w);
    }
  }
  red[tid] = s; __syncthreads();
  for (int st = 128; st > 0; st >>= 1) {
    if (tid < st) red[tid] += red[tid + st];
    __syncthreads();
  }
  if (tid == 0) rs[row] = red[0];
}

// ---------- fp64 GEMM (x@W) with fused dinv scale, 3-plane ZT split, and
// optional fused up-scatter-add on A (A := A + gather(pool) via inv) ----------
__global__ __launch_bounds__(256) void gemm64_f64(
    const void* __restrict__ Ap, long lda, int abf,
    const void* __restrict__ Bp, long ldb, int bbf,
    float* __restrict__ C, long ldc, int M, int N, int K,
    const double* __restrict__ rsum, u16* __restrict__ ZT, const int* __restrict__ dtf,
    const float* __restrict__ ua_pool, const int* __restrict__ ua_inv)
{
  const int abf_ = get_bf(abf, dtf);
  const int bbf_ = get_bf(bbf, dtf);
  __shared__ float As[16][64];
  __shared__ float Bs[16][64];
  const int tid = threadIdx.x;
  const int tr = tid >> 4, tc = tid & 15;
  const long row0 = (long)blockIdx.y * 64;
  const long col0 = (long)blockIdx.x * 64;
  double acc[4][4];
  #pragma unroll
  for (int i = 0; i < 4; ++i)
    #pragma unroll
    for (int j = 0; j < 4; ++j) acc[i][j] = 0.0;

  const int am = tid >> 2;
  const int ak = (tid & 3) * 4;
  const int bk = tid >> 4;
  const int bn = (tid & 15) * 4;
  const long gmA = row0 + am;
  const int uar = (ua_inv && gmA < M) ? ua_inv[gmA] : -1;

  for (int k0 = 0; k0 < K; k0 += 16) {
    float va[4] = {0.f, 0.f, 0.f, 0.f};
    {
      long gm = row0 + am; long gk = k0 + ak;
      if (gm < M && gk < K) {
        if (ua_inv) {
          // fused upadd: callers guarantee lda==K==200, gk%4==0, gk+3<K
          float4 x = *(const float4*)((const float*)Ap + gm * lda + gk);
          if (uar >= 0) {
            const float4 pv = *(const float4*)(ua_pool + (long)uar * lda + gk);
            x.x += pv.x; x.y += pv.y; x.z += pv.z; x.w += pv.w;
          }
          va[0] = x.x; va[1] = x.y; va[2] = x.z; va[3] = x.w;
        } else {
          ld4(Ap, abf_, gm * lda + gk, gk, K, va);
        }
      }
    }
    As[ak + 0][am] = va[0]; As[ak + 1][am] = va[1];
    As[ak + 2][am] = va[2]; As[ak + 3][am] = va[3];

    float vb[4] = {0.f, 0.f, 0.f, 0.f};
    {
      long gk = k0 + bk; long gn = col0 + bn;
      if (gk < K && gn < N) ld4(Bp, bbf_, gk * ldb + gn, gn, N, vb);
    }
    Bs[bk][bn + 0] = vb[0]; Bs[bk][bn + 1] = vb[1];
    Bs[bk][bn + 2] = vb[2]; Bs[bk][bn + 3] = vb[3];

    __syncthreads();
    #pragma unroll
    for (int kk = 0; kk < 16; ++kk) {
      float a[4], b[4];
      #pragma unroll
      for (int i = 0; i < 4; ++i) a[i] = As[kk][tr * 4 + i];
      #pragma unroll
      for (int j = 0; j < 4; ++j) b[j] = Bs[kk][tc * 4 + j];
      #pragma unroll
      for (int i = 0; i < 4; ++i)
        #pragma unroll
        for (int j = 0; j < 4; ++j)
          acc[i][j] += (double)a[i] * (double)b[j];
    }
    __syncthreads();
  }
  #pragma unroll
  for (int i = 0; i < 4; ++i) {
    long gm = row0 + tr * 4 + i;
    if (gm >= M) continue;
    float sc = rsum ? (float)(1.0 / sqrt(rsum[gm] + 2.0)) : 1.f;
    #pragma unroll
    for (int j = 0; j < 4; ++j) {
      long gn = col0 + tc * 4 + j;
      if (gn < N) {
        float v0 = (float)acc[i][j];
        float v = v0 * sc;
        C[gm * ldc + gn] = v;
        if (ZT) {
          u16 hi, mi, lo; split3(v, hi, mi, lo);
          ZT[((long)0 * 208 + gn) * M + gm] = hi;
          ZT[((long)1 * 208 + gn) * M + gm] = mi;
          ZT[((long)2 * 208 + gn) * M + gm] = lo;
        }
      }
    }
  }
}

// ---------- small kernels ----------
struct UpBatch {
  const void* src[19];
  float* dst[19];
  int n[19];
};

__global__ void upcast_batch_k(UpBatch ub, const int* __restrict__ dtf) {
  int bf = *dtf;
  int a = blockIdx.y;
  int i = blockIdx.x * 256 + threadIdx.x;
  if (i < ub.n[a]) ub.dst[a][i] = ld1(ub.src[a], bf, i);
}

// ---------- rank-select top-k (exact, same key/tie-break as bitonic version) ----------
__global__ __launch_bounds__(256) void rank_part_k(
    const float* __restrict__ score, int n, int ns, int* __restrict__ prank)
{
  __shared__ u64 sk[256];
  const int tid = threadIdx.x;
  const int s = blockIdx.x;
  const int slice = n / ns;
  const int jb = s * slice;
  for (int j = tid; j < slice; j += 256) {
    int gj = jb + j;
    u32 b = __float_as_uint(score[gj]);
    u32 u = (b & 0x80000000u) ? ~b : (b | 0x80000000u);
    sk[j] = ((u64)u << 32) | (u32)(~(u32)gj);
  }
  __syncthreads();
  const int i0 = tid * 16;
  if (i0 >= n) return;
  u64 myk[16];
  int cnt[16];
  #pragma unroll
  for (int e = 0; e < 16; ++e) {
    int i = i0 + e;
    u64 key = 0ULL;
    if (i < n) {
      u32 b = __float_as_uint(score[i]);
      u32 u = (b & 0x80000000u) ? ~b : (b | 0x80000000u);
      key = ((u64)u << 32) | (u32)(~(u32)i);
    }
    myk[e] = key; cnt[e] = 0;
  }
  #pragma unroll 4
  for (int j = 0; j < slice; ++j) {
    u64 kj = sk[j];
    #pragma unroll
    for (int e = 0; e < 16; ++e) cnt[e] += (kj > myk[e]) ? 1 : 0;
  }
  #pragma unroll
  for (int e = 0; e < 16; ++e) {
    int i = i0 + e;
    if (i < n) prank[s * n + i] = cnt[e];
  }
}

__global__ void rank_scatter_k(const int* __restrict__ prank, int n, int ns, int k,
                               int* __restrict__ perm, int* __restrict__ inv) {
  int i = blockIdx.x * 256 + threadIdx.x;
  if (i >= n) return;
  int r = 0;
  for (int s = 0; s < ns; ++s) r += prank[s * n + i];
  inv[i] = (r < k) ? r : -1;
  if (r < k) perm[r] = i;
}

// fused matvec2 + log-softmax output, vectorized A loads
__global__ void matvec2_final_k(const void* __restrict__ A, int abf, int n,
                                const float* __restrict__ Zs, const double* __restrict__ rs0,
                                const float* __restrict__ b2, float* __restrict__ out,
                                const int* __restrict__ dtf) {
  const int bf = get_bf(abf, dtf);
  int row = blockIdx.x, tid = threadIdx.x;
  const long base = (long)row * n;
  double s0 = 0.0, s1 = 0.0;
  for (int j4 = tid; j4 < (n >> 2); j4 += 256) {
    const int j = j4 << 2;
    float a0, a1, a2, a3;
    if (bf) {
      ushort4 u = *(const ushort4*)((const u16*)A + base + j);
      a0 = bf2f(u.x); a1 = bf2f(u.y); a2 = bf2f(u.z); a3 = bf2f(u.w);
    } else {
      float4 f = *(const float4*)((const float*)A + base + j);
      a0 = f.x; a1 = f.y; a2 = f.z; a3 = f.w;
    }
    const float4 z01 = *(const float4*)(Zs + 2 * j);
    const float4 z23 = *(const float4*)(Zs + 2 * j + 4);
    s0 += (double)a0 * (double)z01.x; s1 += (double)a0 * (double)z01.y;
    s0 += (double)a1 * (double)z01.z; s1 += (double)a1 * (double)z01.w;
    s0 += (double)a2 * (double)z23.x; s1 += (double)a2 * (double)z23.y;
    s0 += (double)a3 * (double)z23.z; s1 += (double)a3 * (double)z23.w;
  }
  __shared__ double r0[256], r1[256];
  r0[tid] = s0; r1[tid] = s1; __syncthreads();
  for (int st = 128; st > 0; st >>= 1) {
    if (tid < st) { r0[tid] += r0[tid + st]; r1[tid] += r1[tid + st]; }
    __syncthreads();
  }
  if (tid == 0) {
    double y0 = (double)((float)r0[0]);
    double y1 = (double)((float)r1[0]);
    double di = (double)((float)(1.0 / sqrt(rs0[row] + 2.0)));
    double t0 = di * (y0 + 2.0 * (double)Zs[2 * row]) + (double)b2[0];
    double t1 = di * (y1 + 2.0 * (double)Zs[2 * row + 1]) + (double)b2[1];
    double mx = fmax(t0, t1);
    double l = mx + log(exp(t0 - mx) + exp(t1 - mx));
    out[2 * row] = (float)(t0 - l);
    out[2 * row + 1] = (float)(t1 - l);
  }
}

// ---------- host orchestration ----------
extern "C" void kernel_launch(void* const* d_in, const int* in_sizes, int n_in,
                              void* d_out, int out_size, void* d_ws, size_t ws_size,
                              hipStream_t stream) {
  const int N0 = 4096, H = 200;
  const int K1 = 3072, K2 = 1536, K3 = 768;
  const int TK_NS = 64;

  const void* in_x = d_in[0];
  const void* adj  = d_in[1];
  const void* w0 = d_in[2];  const void* b0 = d_in[3];
  const void* w1 = d_in[4];  const void* b1 = d_in[5];
  const void* w2 = d_in[6];  const void* b2 = d_in[7];
  const void* w3 = d_in[8];  const void* b3 = d_in[9];
  const void* p1 = d_in[10]; const void* p2 = d_in[11];
  const void* p3 = d_in[12];
  const void* u0w = d_in[13]; const void* u0b = d_in[14];
  const void* u1w = d_in[15]; const void* u1b = d_in[16];
  const void* u2w = d_in[17]; const void* u2b = d_in[18];

  char* wp = (char*)d_ws;
  auto alloc = [&](size_t bytes) -> void* {
    void* p = (void*)wp;
    wp += (bytes + 255) & ~(size_t)255;
    return p;
  };
  size_t partsBytes = (size_t)300 * 4 * 16384 * 4 + 1024;
  float* parts = (float*)alloc(partsBytes);
  s8*    Agb  = (s8*)alloc((size_t)K1 * N0);   // i8 augment operand (coexists w/ parts)
  u16* Ag3h = (u16*)alloc((size_t)K3 * K2 * 2);
  u16* Ag3l = (u16*)alloc((size_t)K3 * K2 * 2);
  u16* Ah0 = (u16*)alloc((size_t)N0 * N0 * 2);
  u16* Ah1 = (u16*)alloc((size_t)K1 * K1 * 2);
  u16* Ah2 = (u16*)alloc((size_t)K2 * K2 * 2);
  u16* Al2 = (u16*)alloc((size_t)K2 * K2 * 2);
  u16* Ah3 = (u16*)alloc((size_t)K3 * K3 * 2);
  u16* Al3 = (u16*)alloc((size_t)K3 * K3 * 2);
  u16* ZT  = (u16*)alloc((size_t)3 * 208 * N0 * 2);
  float* xs0  = (float*)alloc((size_t)N0 * H * 4);
  float* xs1  = (float*)alloc((size_t)K1 * H * 4);
  float* xs2  = (float*)alloc((size_t)K2 * H * 4);
  float* xcur = (float*)alloc((size_t)N0 * H * 4);
  float* xtmp = (float*)alloc((size_t)N0 * H * 4);
  float* Zbuf = (float*)alloc((size_t)N0 * H * 4);
  float* Xinf = (float*)alloc((size_t)N0 * 3 * 4);
  double* rs0 = (double*)alloc((size_t)N0 * 8);
  double* rs1 = (double*)alloc((size_t)K1 * 8);   // rs1..rs3 + dtflag contiguous, one memset
  double* rs2 = (double*)alloc((size_t)K2 * 8);
  double* rs3 = (double*)alloc((size_t)K3 * 8);
  int* dtflag = (int*)alloc(256);
  float* scores = (float*)alloc((size_t)N0 * 4);
  int* prank = (int*)alloc((size_t)TK_NS * N0 * 4);
  int* perm1 = (int*)alloc((size_t)K1 * 4);
  int* perm2 = (int*)alloc((size_t)K2 * 4);
  int* perm3 = (int*)alloc((size_t)K3 * 4);
  int* inv1 = (int*)alloc((size_t)N0 * 4);
  int* inv2 = (int*)alloc((size_t)K1 * 4);
  int* inv3 = (int*)alloc((size_t)K2 * 4);
  float* w0f = (float*)alloc(3 * H * 4);  float* b0f = (float*)alloc(H * 4);
  float* w1f = (float*)alloc(H * H * 4);  float* b1f = (float*)alloc(H * 4);
  float* w2f = (float*)alloc(H * H * 4);  float* b2f = (float*)alloc(H * 4);
  float* w3f = (float*)alloc(H * H * 4);  float* b3f = (float*)alloc(H * 4);
  float* p1f = (float*)alloc(H * 4);
  float* p2f = (float*)alloc(H * 4);
  float* p3f = (float*)alloc(H * 4);
  float* u0wf = (float*)alloc(H * H * 4); float* u0bf = (float*)alloc(H * 4);
  float* u1wf = (float*)alloc(H * H * 4); float* u1bf = (float*)alloc(H * 4);
  float* u2wf = (float*)alloc(H * 2 * 4); float* u2bf = (float*)alloc(2 * 4);
  (void)in_sizes; (void)n_in; (void)out_size; (void)ws_size; (void)xtmp;

  // zero rs1..rs3 + dtflag in one memset (contiguous, 256B multiples)
  hipMemsetAsync(rs1, 0, (size_t)(K1 + K2 + K3) * 8 + 256, stream);
  detect_k<<<dim3(2048), dim3(256), 0, stream>>>((const u32*)adj, (long)N0 * N0 / 2, dtflag);

  {
    UpBatch ub;
    const void* srcs[19] = {in_x, w0, b0, w1, b1, w2, b2, w3, b3, p1, p2, p3,
                            u0w, u0b, u1w, u1b, u2w, u2b, u2b};
    float* dsts[19] = {Xinf, w0f, b0f, w1f, b1f, w2f, b2f, w3f, b3f, p1f, p2f, p3f,
                       u0wf, u0bf, u1wf, u1bf, u2wf, u2bf, u2bf};
    int ns[19] = {N0 * 3, 3 * H, H, H * H, H, H * H, H, H * H, H, H, H, H,
                  H * H, H, H * H, H, H * 2, 2, 2};
    for (int i = 0; i < 19; ++i) { ub.src[i] = srcs[i]; ub.dst[i] = dsts[i]; ub.n[i] = ns[i]; }
    upcast_batch_k<<<dim3((N0 * 3 + 255) / 256, 19), dim3(256), 0, stream>>>(ub, dtflag);
  }

  a_from_adj_rs_k<<<dim3(N0), dim3(256), 0, stream>>>(adj, dtflag, N0, Ah0, rs0);

  auto gemm64 = [&](const void* A, long lda, int abf, const void* B, long ldb, int bbf,
                    float* C, long ldc, int M, int Nn, int K, const double* rsum, u16* zt,
                    const float* uaPool, const int* uaInv) {
    dim3 g((Nn + 63) / 64, (M + 63) / 64);
    gemm64_f64<<<g, dim3(256), 0, stream>>>(A, lda, abf, B, ldb, bbf, C, ldc, M, Nn, K,
                                            rsum, zt, dtflag, uaPool, uaInv);
  };

  // GCN: out = maybe_relu(dinv .* (A@Zs + 2 Zs) + b); optional fused pooling score.
  auto gcn = [&](const u16* Ah, const u16* Al, int n, int chunks, const double* rs,
                 const float* Xin_, int din, const float* W, const float* bb,
                 float* out, const float* pwf, float* scoreOut,
                 const float* uaPool, const int* uaInv) {
    gemm64(Xin_, din, 0, W, H, 0, Zbuf, H, n, H, din, rs, ZT, uaPool, uaInv);
    if (Al)
      agg_mfma8z<1><<<dim3(n / 128, chunks, 2), dim3(512), 0, stream>>>(
          Ah, Al, ZT, parts, n, (n / 32) / chunks);
    else
      agg_mfma8z<0><<<dim3(n / 128, chunks, 2), dim3(512), 0, stream>>>(
          Ah, nullptr, ZT, parts, n, (n / 32) / chunks);
    reduce_epi_k<<<dim3(n), dim3(256), 0, stream>>>(
        parts, Zbuf, rs, bb, out, n, chunks, 1, pwf, scoreOut);
  };

  auto topk = [&](const float* sc, int n, int k, int* perm, int* inv) {
    rank_part_k<<<dim3(TK_NS), dim3(256), 0, stream>>>(sc, n, TK_NS, prank);
    rank_scatter_k<<<dim3((unsigned)((n + 255) / 256)), dim3(256), 0, stream>>>(
        prank, n, TK_NS, k, perm, inv);
  };

  // ---------------- forward ----------------
  gcn(Ah0, nullptr, N0, 8, rs0, Xinf, 3, w0f, b0f, xs0, p1f, scores, nullptr, nullptr);

  // down 0: i8 SYRK, single-pass 8-wave BK=128 (dbuf + direct write + mirror + rowsum)
  topk(scores, N0, K1, perm1, inv1);
  {
    unsigned nbB = (unsigned)(((long)K1 * N0 / 4 + 255) / 256);
    unsigned nbG = (unsigned)(((long)K1 * 50 + 255) / 256);
    bg_i8_k<<<dim3(nbB + nbG), dim3(256), 0, stream>>>(
        Ah0, 1, N0, perm1, K1, Agb, dtflag, xs0, scores, xcur, nbB);
    int nt = K1 / 128;
    int ntri = nt * (nt + 1) / 2;  // 300
    syrk_tri_i8_full<<<dim3(ntri), dim3(512), 0, stream>>>(
        Agb, N0, N0, K1, Ah1, nullptr, rs1);
  }
  gcn(Ah1, nullptr, K1, 8, rs1, xcur, H, w1f, b1f, xs1, p2f, scores, nullptr, nullptr);

  // down 1: i8 SYRK K-split int32 parts (S=8 -> 624 blocks); fused reduce+rowsum
  topk(scores, K1, K2, perm2, inv2);
  {
    unsigned nbB = (unsigned)(((long)K2 * K1 / 4 + 255) / 256);
    unsigned nbG = (unsigned)(((long)K2 * 50 + 255) / 256);
    bg_i8_k<<<dim3(nbB + nbG), dim3(256), 0, stream>>>(
        Ah1, 1, K1, perm2, K2, Agb, dtflag, xs1, scores, xcur, nbB);
    int nt = K2 / 128;
    int ntri = nt * (nt + 1) / 2;  // 78
    syrk_tri_i8_parts<int><<<dim3(ntri, 8), dim3(256), 0, stream>>>(
        Agb, K1, K1 / 8, ntri, (int*)parts);
    reduce_tri_i8_k<int><<<dim3(ntri * 4), dim3(256), 0, stream>>>(
        (const int*)parts, ntri, K2, 8, Ah2, Al2, rs2);
  }
  gcn(Ah2, Al2, K2, 12, rs2, xcur, H, w2f, b2f, xs2, p3f, scores, nullptr, nullptr);

  // down 2: bf16 2-plane K-split triangle (Ah3/Al3 + rowsum in reduce)
  topk(scores, K2, K3, perm3, inv3);
  {
    unsigned nbB = (unsigned)(((long)K3 * K2 / 4 + 255) / 256);
    unsigned nbG = (unsigned)(((long)K3 * 50 + 255) / 256);
    bg_sp_k<<<dim3(nbB + nbG), dim3(256), 0, stream>>>(
        Ah2, Al2, K2, perm3, K3, Ag3h, Ag3l, xs2, scores, xcur, nbB);
    int nt = K3 / 128;
    syrk_tri2_parts<<<dim3(nt * (nt + 1) / 2, 8), dim3(256), 0, stream>>>(
        Ag3h, Ag3l, K2, parts, K3, K2 / 8);
    long nn = (long)K3 * K3;
    reduce_tri_mirror_k<<<dim3((unsigned)(nn / 256)), dim3(256), 0, stream>>>(
        parts, Ah3, Al3, rs3, K3, 8);
  }
  gcn(Ah3, Al3, K3, 24, rs3, xcur, H, w3f, b3f, xcur, nullptr, nullptr, nullptr, nullptr);

  // up 0: j=2  (A = xs2 + upscatter(xcur) fused into the GEMM)
  gcn(Ah2, Al2, K2, 12, rs2, xs2, H, u0wf, u0bf, xcur, nullptr, nullptr, xcur, inv3);

  // up 1: j=1
  gcn(Ah1, nullptr, K1, 8, rs1, xs1, H, u1wf, u1bf, xcur, nullptr, nullptr, xcur, inv2);

  // up 2: j=0 (final, f64; A = xs0 + upscatter(xcur)); matvec reads bf16 Ah0.
  gemm64(xs0, H, 0, u2wf, 2, 0, Zbuf, 2, N0, 2, H, rs0, nullptr, xcur, inv1);
  matvec2_final_k<<<dim3(N0), dim3(256), 0, stream>>>(
      Ah0, 1, N0, Zbuf, rs0, u2bf, (float*)d_out, dtflag);
}

// Round 10
// 744.967 us; speedup vs baseline: 1.0457x; 1.0457x over previous
//
#include <hip/hip_runtime.h>

typedef unsigned short u16;
typedef unsigned int u32;
typedef unsigned long long u64;
typedef signed char s8;
typedef __attribute__((ext_vector_type(8))) short bfrag8;
typedef __attribute__((ext_vector_type(4))) float f32x4;
typedef __attribute__((ext_vector_type(4))) int i32x4;
typedef __attribute__((address_space(1))) const void gconst_void;
typedef __attribute__((address_space(3))) void lds_void_t;

// ---------- helpers ----------
__device__ __forceinline__ float bf2f(u16 u) {
  return __uint_as_float(((u32)u) << 16);
}
__device__ __forceinline__ u16 f2bf(float f) {
  u32 u = __float_as_uint(f);
  u32 r = (u + 0x7FFFu + ((u >> 16) & 1u)) >> 16;  // RTNE
  return (u16)r;
}
__device__ __forceinline__ void split3(float v, u16& hi, u16& mi, u16& lo) {
  hi = f2bf(v); float r1 = v - bf2f(hi);
  mi = f2bf(r1); float r2 = r1 - bf2f(mi);
  lo = f2bf(r2);
}
__device__ __forceinline__ float ld1(const void* p, int isbf, long idx) {
  return isbf ? bf2f(((const u16*)p)[idx]) : ((const float*)p)[idx];
}
__device__ __forceinline__ void ld4(const void* p, int isbf, long base, long gc, long bound, float v[4]) {
  if (gc + 3 < bound && ((base & 3) == 0)) {
    if (isbf) {
      const ushort4 u = *(const ushort4*)((const u16*)p + base);
      v[0] = bf2f(u.x); v[1] = bf2f(u.y); v[2] = bf2f(u.z); v[3] = bf2f(u.w);
    } else {
      const float4 f = *(const float4*)((const float*)p + base);
      v[0] = f.x; v[1] = f.y; v[2] = f.z; v[3] = f.w;
    }
  } else {
    #pragma unroll
    for (int d = 0; d < 4; ++d) v[d] = (gc + d < bound) ? ld1(p, isbf, base + d) : 0.f;
  }
}

// ---------- input dtype autodetect (uint4 vectorized) ----------
__global__ void detect_k(const u32* __restrict__ a, long nw, int* __restrict__ flag) {
  long nv = nw >> 2;
  long stride = (long)gridDim.x * 256;
  int f = 0;
  for (long j = (long)blockIdx.x * 256 + threadIdx.x; j < nv; j += stride) {
    uint4 w = ((const uint4*)a)[j];
    if (w.x == 0x00003F80u || w.x == 0x3F803F80u ||
        w.y == 0x00003F80u || w.y == 0x3F803F80u ||
        w.z == 0x00003F80u || w.z == 0x3F803F80u ||
        w.w == 0x00003F80u || w.w == 0x3F803F80u) f = 1;
  }
  if (__any(f)) {
    if ((threadIdx.x & 63) == 0) atomicOr(flag, 1);
  }
}

__device__ __forceinline__ int get_bf(int abf, const int* dtf) {
  return (abf >= 0) ? abf : *dtf;
}

// ---------- async global->LDS stage ----------
__device__ __forceinline__ void stageB16(const void* g, void* lds) {
#if __has_builtin(__builtin_amdgcn_global_load_lds)
  __builtin_amdgcn_global_load_lds((gconst_void*)g, (lds_void_t*)lds, 16, 0, 0);
#else
  int lane = threadIdx.x & 63;
  *(int4*)((char*)lds + lane * 16) = *(const int4*)g;
#endif
}

// ---------- i8 triangle SYRK, single-pass, 8 waves (512 thr): dbuf pipeline +
// direct bf16 write + LDS-transpose mirror + exact f64 row sums.
// Integer-exact => the 8-wave output remap is bit-identical to the 4-wave one.
// BK=64: LDS row stride 64B keeps ds_read_b128 at the bank data-volume floor
// (BK=128 regressed: row drops out of bank index -> 16-way conflicts, R9).
__global__ __launch_bounds__(512) void syrk_tri_i8_full(
    const s8* __restrict__ Ag, int ldk, int K, int ldc,
    u16* __restrict__ Ah, u16* __restrict__ Al, double* __restrict__ rsum)
{
  __shared__ s8 At[2][128 * 64];
  __shared__ s8 Bt[2][128 * 64];
  __shared__ int tb[8][16][17];
  const int t = blockIdx.x;
  int ti = (int)((sqrtf((float)(8 * t + 1)) - 1.0f) * 0.5f);
  while ((ti + 1) * (ti + 2) / 2 <= t) ++ti;
  while (ti * (ti + 1) / 2 > t) --ti;
  const int tj = t - ti * (ti + 1) / 2;

  const int tid = threadIdx.x;
  const int wave = tid >> 6, lane = tid & 63;
  const int wr = wave >> 1;   // 0..3: rows wr*32 .. wr*32+31
  const int wc = wave & 1;    // 0..1: cols wc*64 .. wc*64+63
  const long rowA0 = (long)ti * 128;
  const long rowB0 = (long)tj * 128;
  const int nsteps = K / 64;

  i32x4 acc[2][4];
  #pragma unroll
  for (int i = 0; i < 2; ++i)
    #pragma unroll
    for (int j = 0; j < 4; ++j) acc[i][j] = (i32x4)0;

  const int srow = lane >> 2;
  const int scol = (lane & 3) * 16;
  const int m = lane & 15, q = lane >> 4;

  auto stage = [&](int buf, int k0) {
    const int r = wave * 16;
    stageB16(Ag + (rowA0 + r + srow) * (long)ldk + k0 + scol, At[buf] + r * 64);
    stageB16(Ag + (rowB0 + r + srow) * (long)ldk + k0 + scol, Bt[buf] + r * 64);
  };

  stage(0, 0);
  __syncthreads();
  int cur = 0;
  for (int st = 0; st < nsteps; ++st) {
    if (st + 1 < nsteps) stage(cur ^ 1, (st + 1) * 64);

    i32x4 af[2], bf[4];
    #pragma unroll
    for (int mt = 0; mt < 2; ++mt)
      af[mt] = *(const i32x4*)(At[cur] + (wr * 32 + mt * 16 + m) * 64 + q * 16);
    #pragma unroll
    for (int nt = 0; nt < 4; ++nt)
      bf[nt] = *(const i32x4*)(Bt[cur] + (wc * 64 + nt * 16 + m) * 64 + q * 16);
    #pragma unroll
    for (int mt = 0; mt < 2; ++mt)
      #pragma unroll
      for (int nt = 0; nt < 4; ++nt)
        acc[mt][nt] = __builtin_amdgcn_mfma_i32_16x16x64_i8(af[mt], bf[nt], acc[mt][nt], 0, 0, 0);
    if (st + 1 < nsteps) __syncthreads();
    cur ^= 1;
  }

  // epilogue: direct write + exact row sums (f64 atomics; integer-exact)
  #pragma unroll
  for (int mt = 0; mt < 2; ++mt) {
    double rp[4] = {0.0, 0.0, 0.0, 0.0};
    #pragma unroll
    for (int nt = 0; nt < 4; ++nt) {
      const long gr0 = rowA0 + wr * 32 + mt * 16 + q * 4;
      const long gc = rowB0 + wc * 64 + nt * 16 + m;
      #pragma unroll
      for (int r = 0; r < 4; ++r) {
        const long gr = gr0 + r;
        int iv = (gr == gc) ? 0 : acc[mt][nt][r];
        float fv = (float)iv;
        long idx = gr * ldc + gc;
        u16 h = f2bf(fv);
        Ah[idx] = h;
        if (Al) Al[idx] = f2bf(fv - bf2f(h));
        rp[r] += (double)iv;
      }
    }
    #pragma unroll
    for (int r = 0; r < 4; ++r) {
      double v = rp[r];
      for (int off = 8; off > 0; off >>= 1) v += __shfl_down(v, off);
      if (m == 0) atomicAdd(&rsum[rowA0 + wr * 32 + mt * 16 + q * 4 + r], v);
    }
  }
  if (ti != tj) {
    #pragma unroll
    for (int nt = 0; nt < 4; ++nt) {
      double cp = 0.0;
      #pragma unroll
      for (int mt = 0; mt < 2; ++mt) {
        #pragma unroll
        for (int r = 0; r < 4; ++r) tb[wave][q * 4 + r][m] = acc[mt][nt][r];
        const long baseR = rowB0 + wc * 64 + nt * 16;
        const long baseC = rowA0 + wr * 32 + mt * 16;
        #pragma unroll
        for (int r = 0; r < 4; ++r) {
          float tv = (float)tb[wave][m][q * 4 + r];
          long idx = (baseR + q * 4 + r) * ldc + baseC + m;
          u16 h = f2bf(tv);
          Ah[idx] = h;
          if (Al) Al[idx] = f2bf(tv - bf2f(h));
        }
        #pragma unroll
        for (int r = 0; r < 4; ++r) cp += (double)acc[mt][nt][r];
      }
      double v = cp;
      v += __shfl_down(v, 32);
      v += __shfl_down(v, 16);
      if (q == 0) atomicAdd(&rsum[rowB0 + wc * 64 + nt * 16 + m], v);
    }
  }
}

// ---------- i8 triangle SYRK, K-split -> PT parts (exact partials) ----------
template<typename PT>
__global__ __launch_bounds__(256) void syrk_tri_i8_parts(
    const s8* __restrict__ Ag, int ldk, int Ksplit, int ntri,
    PT* __restrict__ parts)
{
  __shared__ s8 At[2][128 * 64];
  __shared__ s8 Bt[2][128 * 64];
  const int t = blockIdx.x;
  int ti = (int)((sqrtf((float)(8 * t + 1)) - 1.0f) * 0.5f);
  while ((ti + 1) * (ti + 2) / 2 <= t) ++ti;
  while (ti * (ti + 1) / 2 > t) --ti;
  const int tj = t - ti * (ti + 1) / 2;

  const int tid = threadIdx.x;
  const int wave = tid >> 6, lane = tid & 63;
  const int wr = wave >> 1, wc = wave & 1;
  const long rowA0 = (long)ti * 128;
  const long rowB0 = (long)tj * 128;
  const int kbeg = blockIdx.y * Ksplit;
  const int nsteps = Ksplit / 64;

  i32x4 acc[4][4];
  #pragma unroll
  for (int i = 0; i < 4; ++i)
    #pragma unroll
    for (int j = 0; j < 4; ++j) acc[i][j] = (i32x4)0;

  const int srow = lane >> 2;
  const int scol = (lane & 3) * 16;
  const int m = lane & 15, q = lane >> 4;

  auto stage = [&](int buf, int k0) {
    #pragma unroll
    for (int tt = 0; tt < 2; ++tt) {
      const int r = wave * 32 + tt * 16;
      stageB16(Ag + (rowA0 + r + srow) * (long)ldk + k0 + scol, At[buf] + r * 64);
      stageB16(Ag + (rowB0 + r + srow) * (long)ldk + k0 + scol, Bt[buf] + r * 64);
    }
  };

  stage(0, kbeg);
  __syncthreads();
  int cur = 0;
  for (int st = 0; st < nsteps; ++st) {
    if (st + 1 < nsteps) stage(cur ^ 1, kbeg + (st + 1) * 64);

    i32x4 af[4], bf[4];
    #pragma unroll
    for (int mt = 0; mt < 4; ++mt)
      af[mt] = *(const i32x4*)(At[cur] + (wr * 64 + mt * 16 + m) * 64 + q * 16);
    #pragma unroll
    for (int nt = 0; nt < 4; ++nt)
      bf[nt] = *(const i32x4*)(Bt[cur] + (wc * 64 + nt * 16 + m) * 64 + q * 16);
    #pragma unroll
    for (int mt = 0; mt < 4; ++mt)
      #pragma unroll
      for (int nt = 0; nt < 4; ++nt)
        acc[mt][nt] = __builtin_amdgcn_mfma_i32_16x16x64_i8(af[mt], bf[nt], acc[mt][nt], 0, 0, 0);
    if (st + 1 < nsteps) __syncthreads();
    cur ^= 1;
  }

  PT* P = parts + ((long)blockIdx.y * ntri + t) * 16384;
  #pragma unroll
  for (int mt = 0; mt < 4; ++mt) {
    #pragma unroll
    for (int nt = 0; nt < 4; ++nt) {
      const int r0 = wr * 64 + mt * 16 + q * 4;
      const int c = wc * 64 + nt * 16 + m;
      #pragma unroll
      for (int r = 0; r < 4; ++r)
        P[(r0 + r) * 128 + c] = (PT)acc[mt][nt][r];
    }
  }
}

// Sum PT parts per tile, zero diag, emit bf16 hi(/lo) planes + coalesced mirror
// via padded LDS transpose; fused EXACT row sums (double atomics on rs).
template<typename PT>
__global__ __launch_bounds__(256) void reduce_tri_i8_k(
    const PT* __restrict__ parts, int ntri, int n, int nz,
    u16* __restrict__ Ah, u16* __restrict__ Al, double* __restrict__ rs)
{
  __shared__ float T[128 * 33];
  const int t = blockIdx.x >> 2;
  const int slab = blockIdx.x & 3;
  int ti = (int)((sqrtf((float)(8 * t + 1)) - 1.0f) * 0.5f);
  while ((ti + 1) * (ti + 2) / 2 <= t) ++ti;
  while (ti * (ti + 1) / 2 > t) --ti;
  const int tj = t - ti * (ti + 1) / 2;
  const long rowA0 = (long)ti * 128;
  const long rowB0 = (long)tj * 128;
  const int r0 = slab * 32;
  const int tid = threadIdx.x;
  const int lane = tid & 63;
  const long tstride = (long)ntri * 16384;

  #pragma unroll
  for (int it = 0; it < 16; ++it) {
    const int idx = it * 256 + tid;       // 0..4095 covers 32x128 slab
    const int lr = idx >> 7;              // local row in slab
    const int lc = idx & 127;             // local col
    long base = (long)t * 16384 + (r0 + lr) * 128 + lc;
    int v = 0;
    for (int z = 0; z < nz; ++z) v += (int)parts[(long)z * tstride + base];
    const long gr = rowA0 + r0 + lr;
    const long gc = rowB0 + lc;
    if (gr == gc) v = 0;
    const float fv = (float)v;
    const u16 h = f2bf(fv);
    const long o = gr * n + gc;
    Ah[o] = h;
    if (Al) Al[o] = f2bf(fv - bf2f(h));
    T[lc * 33 + lr] = fv;                 // transposed store, stride-33: conflict-free
    // exact row-sum partial: all 64 lanes of this wave share row gr
    float wsum = fv;
    #pragma unroll
    for (int off = 32; off > 0; off >>= 1) wsum += __shfl_down(wsum, off);
    if (lane == 0) atomicAdd(&rs[gr], (double)wsum);
  }
  if (ti == tj) return;                   // diag tile fully covers its own block
  __syncthreads();
  #pragma unroll
  for (int it = 0; it < 16; ++it) {
    const int idx = it * 256 + tid;       // covers 128x32 mirror slab
    const int mr = idx >> 5;              // 0..127 mirror row
    const int mc = idx & 31;              // 0..31 mirror col
    const float fv = T[mr * 33 + mc];     // = L[r0+mc][mr]
    const u16 h = f2bf(fv);
    const long o = (rowB0 + mr) * n + rowA0 + r0 + mc;
    Ah[o] = h;
    if (Al) Al[o] = f2bf(fv - bf2f(h));
    // mirror row-sum: 32-lane groups share row (rowB0+mr); lanes 0 and 32 emit
    float ws = fv;
    #pragma unroll
    for (int off = 16; off > 0; off >>= 1) ws += __shfl_down(ws, off);
    if ((lane & 31) == 0) atomicAdd(&rs[rowB0 + mr], (double)ws);
  }
}

// ---------- bf16 2-plane triangle SYRK, K-split parts; double-buffered ----------
__global__ __launch_bounds__(256) void syrk_tri2_parts(
    const u16* __restrict__ Ah, const u16* __restrict__ Al, int ldk,
    float* __restrict__ parts, int n, int per)
{
  __shared__ u16 Ath[2][128 * 32];
  __shared__ u16 Bth[2][128 * 32];
  __shared__ u16 Atl[2][128 * 32];
  __shared__ u16 Btl[2][128 * 32];
  const int t = blockIdx.x;
  int ti = (int)((sqrtf((float)(8 * t + 1)) - 1.0f) * 0.5f);
  while ((ti + 1) * (ti + 2) / 2 <= t) ++ti;
  while (ti * (ti + 1) / 2 > t) --ti;
  const int tj = t - ti * (ti + 1) / 2;

  const int tid = threadIdx.x;
  const int wave = tid >> 6, lane = tid & 63;
  const int wr = wave >> 1, wc = wave & 1;
  const long rowA0 = (long)ti * 128;
  const long rowB0 = (long)tj * 128;
  const int kbeg = blockIdx.y * per;
  const int nsteps = per / 32;

  f32x4 acc[4][4];
  #pragma unroll
  for (int i = 0; i < 4; ++i)
    #pragma unroll
    for (int j = 0; j < 4; ++j) acc[i][j] = (f32x4)0.f;

  const int srow = lane >> 2;
  const int scol = (lane & 3) * 8;
  const int m = lane & 15, q = lane >> 4;

  auto stage = [&](int buf, int k0) {
    #pragma unroll
    for (int tt = 0; tt < 2; ++tt) {
      const int r = wave * 32 + tt * 16;
      stageB16(Ah + (rowA0 + r + srow) * (long)ldk + k0 + scol, Ath[buf] + r * 32);
      stageB16(Ah + (rowB0 + r + srow) * (long)ldk + k0 + scol, Bth[buf] + r * 32);
      stageB16(Al + (rowA0 + r + srow) * (long)ldk + k0 + scol, Atl[buf] + r * 32);
      stageB16(Al + (rowB0 + r + srow) * (long)ldk + k0 + scol, Btl[buf] + r * 32);
    }
  };

  stage(0, kbeg);
  __syncthreads();
  int cur = 0;
  for (int st = 0; st < nsteps; ++st) {
    if (st + 1 < nsteps) stage(cur ^ 1, kbeg + (st + 1) * 32);

    bfrag8 afh[4], afl[4], bfh[4], bfl[4];
    #pragma unroll
    for (int mt = 0; mt < 4; ++mt) {
      afh[mt] = *(const bfrag8*)(Ath[cur] + (wr * 64 + mt * 16 + m) * 32 + q * 8);
      afl[mt] = *(const bfrag8*)(Atl[cur] + (wr * 64 + mt * 16 + m) * 32 + q * 8);
    }
    #pragma unroll
    for (int nt = 0; nt < 4; ++nt) {
      bfh[nt] = *(const bfrag8*)(Bth[cur] + (wc * 64 + nt * 16 + m) * 32 + q * 8);
      bfl[nt] = *(const bfrag8*)(Btl[cur] + (wc * 64 + nt * 16 + m) * 32 + q * 8);
    }
    #pragma unroll
    for (int mt = 0; mt < 4; ++mt)
      #pragma unroll
      for (int nt = 0; nt < 4; ++nt) {
        acc[mt][nt] = __builtin_amdgcn_mfma_f32_16x16x32_bf16(afh[mt], bfh[nt], acc[mt][nt], 0, 0, 0);
        acc[mt][nt] = __builtin_amdgcn_mfma_f32_16x16x32_bf16(afh[mt], bfl[nt], acc[mt][nt], 0, 0, 0);
        acc[mt][nt] = __builtin_amdgcn_mfma_f32_16x16x32_bf16(afl[mt], bfh[nt], acc[mt][nt], 0, 0, 0);
        acc[mt][nt] = __builtin_amdgcn_mfma_f32_16x16x32_bf16(afl[mt], bfl[nt], acc[mt][nt], 0, 0, 0);
      }
    if (st + 1 < nsteps) __syncthreads();
    cur ^= 1;
  }

  float* P = parts + (long)blockIdx.y * n * n;
  #pragma unroll
  for (int mt = 0; mt < 4; ++mt) {
    #pragma unroll
    for (int nt = 0; nt < 4; ++nt) {
      const long gr0 = rowA0 + wr * 64 + mt * 16 + q * 4;
      const long gc = rowB0 + wc * 64 + nt * 16 + m;
      #pragma unroll
      for (int r = 0; r < 4; ++r)
        P[(gr0 + r) * n + gc] = acc[mt][nt][r];
    }
  }
}

// sum nz parts, mirror, zero diag; Ah/Al write + f64 row sums.
__global__ void reduce_tri_mirror_k(const float* __restrict__ parts,
                                    u16* __restrict__ Ah, u16* __restrict__ Al,
                                    double* __restrict__ rsum, int n, int nz) {
  __shared__ double red[256];
  const int tid = threadIdx.x;
  long idx = (long)blockIdx.x * 256 + tid;
  long nn = (long)n * n;
  long r = idx / n, c = idx - r * n;
  double myv = 0.0;
  if (idx < nn) {
    if (r == c) {
      Ah[idx] = 0; Al[idx] = 0;
    } else if (r > c) {
      float s = 0.f;
      for (int z = 0; z < nz; ++z) s += parts[(long)z * nn + r * n + c];
      long mi = c * n + r;
      u16 h = f2bf(s);
      u16 l = f2bf(s - bf2f(h));
      Ah[idx] = h; Al[idx] = l;
      Ah[mi] = h;  Al[mi] = l;
      myv = (double)s;
      atomicAdd(&rsum[c], (double)s);
    }
  }
  red[tid] = myv;
  __syncthreads();
  for (int st = 128; st > 0; st >>= 1) {
    if (tid < st) red[tid] += red[tid + st];
    __syncthreads();
  }
  if (tid == 0 && idx < nn) atomicAdd(&rsum[r], red[0]);
}

// ---------- fused build (i8 augment operand) + gather-x, 4-wide vectorized ----------
__global__ void bg_i8_k(const void* __restrict__ src, int srcbf, int nsrc,
                        const int* __restrict__ perm, int kRows,
                        s8* __restrict__ Ag, const int* __restrict__ dtf,
                        const float* __restrict__ xsrc, const float* __restrict__ score,
                        float* __restrict__ xdst, unsigned nbB) {
  if (blockIdx.x < nbB) {
    long tot4 = ((long)kRows * nsrc) >> 2;
    long i4 = (long)blockIdx.x * 256 + threadIdx.x;
    if (i4 >= tot4) return;
    long idx = i4 << 2;
    int r = (int)(idx / nsrc);
    int c = (int)(idx - (long)r * nsrc);
    int p = perm[r];
    float v[4];
    if (get_bf(srcbf, dtf)) {
      ushort4 u = *(const ushort4*)((const u16*)src + (long)p * nsrc + c);
      v[0] = bf2f(u.x); v[1] = bf2f(u.y); v[2] = bf2f(u.z); v[3] = bf2f(u.w);
    } else {
      float4 f = *(const float4*)((const float*)src + (long)p * nsrc + c);
      v[0] = f.x; v[1] = f.y; v[2] = f.z; v[3] = f.w;
    }
    char4 o;
    o.x = (s8)(int)(v[0] + ((c + 0 == p) ? 1.f : 0.f));
    o.y = (s8)(int)(v[1] + ((c + 1 == p) ? 1.f : 0.f));
    o.z = (s8)(int)(v[2] + ((c + 2 == p) ? 1.f : 0.f));
    o.w = (s8)(int)(v[3] + ((c + 3 == p) ? 1.f : 0.f));
    *(char4*)(Ag + idx) = o;
  } else {
    long tot4 = (long)kRows * 50;  // 200/4
    long i4 = (long)(blockIdx.x - nbB) * 256 + threadIdx.x;
    if (i4 >= tot4) return;
    long idx = i4 << 2;
    int r = (int)(idx / 200);
    int c = (int)(idx - (long)r * 200);
    int p = perm[r];
    float4 x = *(const float4*)(xsrc + (long)p * 200 + c);
    float sc = score[p];
    x.x *= sc; x.y *= sc; x.z *= sc; x.w *= sc;
    *(float4*)(xdst + idx) = x;
  }
}

// fused build (2-plane bf16 from Ah2/Al2) + gather-x, 4-wide vectorized
__global__ void bg_sp_k(const u16* __restrict__ srcH, const u16* __restrict__ srcL,
                        int nsrc, const int* __restrict__ perm, int kRows,
                        u16* __restrict__ Agh, u16* __restrict__ Agl,
                        const float* __restrict__ xsrc, const float* __restrict__ score,
                        float* __restrict__ xdst, unsigned nbB) {
  if (blockIdx.x < nbB) {
    long tot4 = ((long)kRows * nsrc) >> 2;
    long i4 = (long)blockIdx.x * 256 + threadIdx.x;
    if (i4 >= tot4) return;
    long idx = i4 << 2;
    int r = (int)(idx / nsrc);
    int c = (int)(idx - (long)r * nsrc);
    int p = perm[r];
    long si = (long)p * nsrc + c;
    ushort4 uh = *(const ushort4*)(srcH + si);
    ushort4 ul = *(const ushort4*)(srcL + si);
    ushort4 oh, ol;
    {
      float v = bf2f(uh.x) + bf2f(ul.x); if (c + 0 == p) v += 1.f;
      oh.x = f2bf(v); ol.x = f2bf(v - bf2f(oh.x));
    }
    {
      float v = bf2f(uh.y) + bf2f(ul.y); if (c + 1 == p) v += 1.f;
      oh.y = f2bf(v); ol.y = f2bf(v - bf2f(oh.y));
    }
    {
      float v = bf2f(uh.z) + bf2f(ul.z); if (c + 2 == p) v += 1.f;
      oh.z = f2bf(v); ol.z = f2bf(v - bf2f(oh.z));
    }
    {
      float v = bf2f(uh.w) + bf2f(ul.w); if (c + 3 == p) v += 1.f;
      oh.w = f2bf(v); ol.w = f2bf(v - bf2f(oh.w));
    }
    *(ushort4*)(Agh + idx) = oh;
    *(ushort4*)(Agl + idx) = ol;
  } else {
    long tot4 = (long)kRows * 50;
    long i4 = (long)(blockIdx.x - nbB) * 256 + threadIdx.x;
    if (i4 >= tot4) return;
    long idx = i4 << 2;
    int r = (int)(idx / 200);
    int c = (int)(idx - (long)r * 200);
    int p = perm[r];
    float4 x = *(const float4*)(xsrc + (long)p * 200 + c);
    float sc = score[p];
    x.x *= sc; x.y *= sc; x.z *= sc; x.w *= sc;
    *(float4*)(xdst + idx) = x;
  }
}

// ---------- MFMA aggregation: Y = A @ Z ----------
// 8 waves (512 thr); blockIdx.z splits the 13 output col-subtiles 7/6 so LDS
// fits 2 blocks/CU; double-buffered async pipeline.
template<int HASAL>
__global__ __launch_bounds__(512, 4) void agg_mfma8z(
    const u16* __restrict__ Ah, const u16* __restrict__ Al,
    const u16* __restrict__ ZT, float* __restrict__ parts,
    int K, int per_steps)
{
  __shared__ u16 At[2][8 * 512];
  __shared__ u16 Alt[HASAL ? 2 * 8 * 512 : 2];
  __shared__ u16 Zt[2][21 * 512];

  const int tid = threadIdx.x;
  const int wave = tid >> 6, lane = tid & 63;
  const int zh = blockIdx.z;
  const int ct0 = zh ? 7 : 0;                  // global subtile base
  const int nts = zh ? 6 : 7;                  // subtiles this block
  const int cth = (nts + 1) >> 1;              // per-col-half split (4/3 or 3/3)
  const int rg = wave & 3;                     // row group: rows rg*32..rg*32+31
  const int cg = wave >> 2;                    // col half within block
  const int wct0 = cg ? cth : 0;
  const int wnct = cg ? (nts - cth) : cth;
  const long row0 = (long)blockIdx.x * 128;
  const int chunk = blockIdx.y;
  const int kbeg = chunk * per_steps * 32;
  const int nsteps = (min(K, kbeg + per_steps * 32) - kbeg) / 32;
  const int m = lane & 15, q = lane >> 4;
  const int srow = lane >> 2, scol = (lane & 3) * 8;
  const int nstg = (HASAL ? 16 : 8) + 3 * nts;

  auto stage = [&](int buf, int k0) {
    for (int s = wave; s < nstg; s += 8) {
      if (s < 8) {
        stageB16(Ah + (row0 + s * 16 + srow) * (long)K + k0 + scol, At[buf] + s * 512);
      } else if (HASAL && s < 16) {
        stageB16(Al + (row0 + (s - 8) * 16 + srow) * (long)K + k0 + scol,
                 (u16*)Alt + (buf * 8 + (s - 8)) * 512);
      } else {
        const int zz = s - (HASAL ? 16 : 8);
        const int pl = (zz >= 2 * nts) ? 2 : ((zz >= nts) ? 1 : 0);
        const int c = zz - pl * nts;
        stageB16(ZT + ((long)(pl * 208 + (ct0 + c) * 16 + srow)) * K + k0 + scol,
                 Zt[buf] + (pl * 7 + c) * 512);
      }
    }
  };

  f32x4 acc[2][4];
  #pragma unroll
  for (int rt = 0; rt < 2; ++rt)
    #pragma unroll
    for (int ct = 0; ct < 4; ++ct) acc[rt][ct] = (f32x4)0.f;

  stage(0, kbeg);
  __syncthreads();
  int cur = 0;
  for (int t = 0; t < nsteps; ++t) {
    if (t + 1 < nsteps) stage(cur ^ 1, kbeg + (t + 1) * 32);  // async prefetch

    const u16* Atb = At[cur];
    const u16* Ztb = Zt[cur];
    bfrag8 af0 = *(const bfrag8*)(Atb + (rg * 2) * 512 + m * 32 + q * 8);
    bfrag8 af1 = *(const bfrag8*)(Atb + (rg * 2 + 1) * 512 + m * 32 + q * 8);
    bfrag8 al0, al1;
    if (HASAL) {
      const u16* Altb = (const u16*)Alt + cur * 8 * 512;
      al0 = *(const bfrag8*)(Altb + (rg * 2) * 512 + m * 32 + q * 8);
      al1 = *(const bfrag8*)(Altb + (rg * 2 + 1) * 512 + m * 32 + q * 8);
    }
    #pragma unroll
    for (int ct = 0; ct < 4; ++ct) {
      if (ct < wnct) {
        const int gct = wct0 + ct;
        bfrag8 b0 = *(const bfrag8*)(Ztb + (0 * 7 + gct) * 512 + m * 32 + q * 8);
        bfrag8 b1 = *(const bfrag8*)(Ztb + (1 * 7 + gct) * 512 + m * 32 + q * 8);
        bfrag8 b2 = *(const bfrag8*)(Ztb + (2 * 7 + gct) * 512 + m * 32 + q * 8);
        acc[0][ct] = __builtin_amdgcn_mfma_f32_16x16x32_bf16(af0, b0, acc[0][ct], 0, 0, 0);
        acc[0][ct] = __builtin_amdgcn_mfma_f32_16x16x32_bf16(af0, b1, acc[0][ct], 0, 0, 0);
        acc[0][ct] = __builtin_amdgcn_mfma_f32_16x16x32_bf16(af0, b2, acc[0][ct], 0, 0, 0);
        acc[1][ct] = __builtin_amdgcn_mfma_f32_16x16x32_bf16(af1, b0, acc[1][ct], 0, 0, 0);
        acc[1][ct] = __builtin_amdgcn_mfma_f32_16x16x32_bf16(af1, b1, acc[1][ct], 0, 0, 0);
        acc[1][ct] = __builtin_amdgcn_mfma_f32_16x16x32_bf16(af1, b2, acc[1][ct], 0, 0, 0);
        if (HASAL) {
          acc[0][ct] = __builtin_amdgcn_mfma_f32_16x16x32_bf16(al0, b0, acc[0][ct], 0, 0, 0);
          acc[0][ct] = __builtin_amdgcn_mfma_f32_16x16x32_bf16(al0, b1, acc[0][ct], 0, 0, 0);
          acc[1][ct] = __builtin_amdgcn_mfma_f32_16x16x32_bf16(al1, b0, acc[1][ct], 0, 0, 0);
          acc[1][ct] = __builtin_amdgcn_mfma_f32_16x16x32_bf16(al1, b1, acc[1][ct], 0, 0, 0);
        }
      }
    }
    if (t + 1 < nsteps) __syncthreads();        // vmcnt(0): prefetch landed; reads done
    cur ^= 1;
  }

  float* P = parts + (long)chunk * gridDim.x * 128 * 208;
  #pragma unroll
  for (int rt = 0; rt < 2; ++rt) {
    #pragma unroll
    for (int ct = 0; ct < 4; ++ct) {
      if (ct < wnct) {
        const long grow0 = row0 + rg * 32 + rt * 16 + q * 4;
        const long gcol = (ct0 + wct0 + ct) * 16 + m;
        #pragma unroll
        for (int r = 0; r < 4; ++r)
          P[(grow0 + r) * 208 + gcol] = acc[rt][ct][r];
      }
    }
  }
}

// fused: reduce parts + GCN epilogue (+ optional pooling score)
__global__ __launch_bounds__(256) void reduce_epi_k(
    const float* __restrict__ parts, const float* __restrict__ Zs,
    const double* __restrict__ rs, const float* __restrict__ b,
    float* __restrict__ out, int n, int nz, int relu,
    const float* __restrict__ pw, float* __restrict__ score)
{
  __shared__ float vrow[200];
  const int i = blockIdx.x, tid = threadIdx.x;
  float dv = (float)(1.0 / sqrt(rs[i] + 2.0));
  if (tid < 200) {
    long base = (long)i * 208 + tid;
    float s = 0.f;
    for (int c = 0; c < nz; ++c) s += parts[(long)c * n * 208 + base];
    float v = dv * (s + 2.f * Zs[(long)i * 200 + tid]) + b[tid];
    if (relu) v = fmaxf(v, 0.f);
    out[(long)i * 200 + tid] = v;
    if (score) vrow[tid] = v;
  }
  if (!score) return;
  __syncthreads();
  if (tid < 64) {
    double ps = 0.0;
    for (int j = tid; j < 200; j += 64) { double w = pw[j]; ps += w * w; }
    for (int off = 32; off > 0; off >>= 1) ps += __shfl_down(ps, off);
    double nrm = sqrt(__shfl(ps, 0));
    double s = 0.0;
    for (int j = tid; j < 200; j += 64) s += (double)vrow[j] * (double)pw[j];
    for (int off = 32; off > 0; off >>= 1) s += __shfl_down(s, off);
    if (tid == 0) score[i] = (float)tanh(s / nrm);
  }
}

// fused adj->bf16 plane + row sums (level 0), vectorized.
__global__ void a_from_adj_rs_k(const void* __restrict__ adj, const int* __restrict__ dtf,
                                int n, u16* __restrict__ Ah, double* __restrict__ rs) {
  __shared__ double red[256];
  int bf = *dtf;
  const int row = blockIdx.x, tid = threadIdx.x;
  const long base = (long)row * n;
  double s = 0.0;
  if (bf) {
    const uint4* src = (const uint4*)((const u16*)adj + base);
    uint4* dst = (uint4*)(Ah + base);
    for (int j = tid; j < (n >> 3); j += 256) {
      uint4 v = src[j];
      dst[j] = v;
      s += (double)(bf2f((u16)(v.x & 0xFFFFu)) + bf2f((u16)(v.x >> 16))
                  + bf2f((u16)(v.y & 0xFFFFu)) + bf2f((u16)(v.y >> 16))
                  + bf2f((u16)(v.z & 0xFFFFu)) + bf2f((u16)(v.z >> 16))
                  + bf2f((u16)(v.w & 0xFFFFu)) + bf2f((u16)(v.w >> 16)));
    }
  } else {
    const float4* src = (const float4*)((const float*)adj + base);
    ushort4* dst = (ushort4*)(Ah + base);
    for (int j = tid; j < (n >> 2); j += 256) {
      float4 v = src[j];
      ushort4 o;
      o.x = f2bf(v.x); o.y = f2bf(v.y); o.z = f2bf(v.z); o.w = f2bf(v.w);
      dst[j] = o;
      s += (double)(v.x + v.y + v.z + v.w);
    }
  }
  red[tid] = s; __syncthreads();
  for (int st = 128; st > 0; st >>= 1) {
    if (tid < st) red[tid] += red[tid + st];
    __syncthreads();
  }
  if (tid == 0) rs[row] = red[0];
}

// ---------- fp64 GEMM (x@W) with fused dinv scale, 3-plane ZT split, and
// optional fused up-scatter-add on A (A := A + gather(pool) via inv) ----------
__global__ __launch_bounds__(256) void gemm64_f64(
    const void* __restrict__ Ap, long lda, int abf,
    const void* __restrict__ Bp, long ldb, int bbf,
    float* __restrict__ C, long ldc, int M, int N, int K,
    const double* __restrict__ rsum, u16* __restrict__ ZT, const int* __restrict__ dtf,
    const float* __restrict__ ua_pool, const int* __restrict__ ua_inv)
{
  const int abf_ = get_bf(abf, dtf);
  const int bbf_ = get_bf(bbf, dtf);
  __shared__ float As[16][64];
  __shared__ float Bs[16][64];
  const int tid = threadIdx.x;
  const int tr = tid >> 4, tc = tid & 15;
  const long row0 = (long)blockIdx.y * 64;
  const long col0 = (long)blockIdx.x * 64;
  double acc[4][4];
  #pragma unroll
  for (int i = 0; i < 4; ++i)
    #pragma unroll
    for (int j = 0; j < 4; ++j) acc[i][j] = 0.0;

  const int am = tid >> 2;
  const int ak = (tid & 3) * 4;
  const int bk = tid >> 4;
  const int bn = (tid & 15) * 4;
  const long gmA = row0 + am;
  const int uar = (ua_inv && gmA < M) ? ua_inv[gmA] : -1;

  for (int k0 = 0; k0 < K; k0 += 16) {
    float va[4] = {0.f, 0.f, 0.f, 0.f};
    {
      long gm = row0 + am; long gk = k0 + ak;
      if (gm < M && gk < K) {
        if (ua_inv) {
          // fused upadd: callers guarantee lda==K==200, gk%4==0, gk+3<K
          float4 x = *(const float4*)((const float*)Ap + gm * lda + gk);
          if (uar >= 0) {
            const float4 pv = *(const float4*)(ua_pool + (long)uar * lda + gk);
            x.x += pv.x; x.y += pv.y; x.z += pv.z; x.w += pv.w;
          }
          va[0] = x.x; va[1] = x.y; va[2] = x.z; va[3] = x.w;
        } else {
          ld4(Ap, abf_, gm * lda + gk, gk, K, va);
        }
      }
    }
    As[ak + 0][am] = va[0]; As[ak + 1][am] = va[1];
    As[ak + 2][am] = va[2]; As[ak + 3][am] = va[3];

    float vb[4] = {0.f, 0.f, 0.f, 0.f};
    {
      long gk = k0 + bk; long gn = col0 + bn;
      if (gk < K && gn < N) ld4(Bp, bbf_, gk * ldb + gn, gn, N, vb);
    }
    Bs[bk][bn + 0] = vb[0]; Bs[bk][bn + 1] = vb[1];
    Bs[bk][bn + 2] = vb[2]; Bs[bk][bn + 3] = vb[3];

    __syncthreads();
    #pragma unroll
    for (int kk = 0; kk < 16; ++kk) {
      float a[4], b[4];
      #pragma unroll
      for (int i = 0; i < 4; ++i) a[i] = As[kk][tr * 4 + i];
      #pragma unroll
      for (int j = 0; j < 4; ++j) b[j] = Bs[kk][tc * 4 + j];
      #pragma unroll
      for (int i = 0; i < 4; ++i)
        #pragma unroll
        for (int j = 0; j < 4; ++j)
          acc[i][j] += (double)a[i] * (double)b[j];
    }
    __syncthreads();
  }
  #pragma unroll
  for (int i = 0; i < 4; ++i) {
    long gm = row0 + tr * 4 + i;
    if (gm >= M) continue;
    float sc = rsum ? (float)(1.0 / sqrt(rsum[gm] + 2.0)) : 1.f;
    #pragma unroll
    for (int j = 0; j < 4; ++j) {
      long gn = col0 + tc * 4 + j;
      if (gn < N) {
        float v0 = (float)acc[i][j];
        float v = v0 * sc;
        C[gm * ldc + gn] = v;
        if (ZT) {
          u16 hi, mi, lo; split3(v, hi, mi, lo);
          ZT[((long)0 * 208 + gn) * M + gm] = hi;
          ZT[((long)1 * 208 + gn) * M + gm] = mi;
          ZT[((long)2 * 208 + gn) * M + gm] = lo;
        }
      }
    }
  }
}

// ---------- small kernels ----------
struct UpBatch {
  const void* src[19];
  float* dst[19];
  int n[19];
};

__global__ void upcast_batch_k(UpBatch ub, const int* __restrict__ dtf) {
  int bf = *dtf;
  int a = blockIdx.y;
  int i = blockIdx.x * 256 + threadIdx.x;
  if (i < ub.n[a]) ub.dst[a][i] = ld1(ub.src[a], bf, i);
}

// ---------- rank-select top-k (exact, same key/tie-break as bitonic version) ----------
__global__ __launch_bounds__(256) void rank_part_k(
    const float* __restrict__ score, int n, int ns, int* __restrict__ prank)
{
  __shared__ u64 sk[256];
  const int tid = threadIdx.x;
  const int s = blockIdx.x;
  const int slice = n / ns;
  const int jb = s * slice;
  for (int j = tid; j < slice; j += 256) {
    int gj = jb + j;
    u32 b = __float_as_uint(score[gj]);
    u32 u = (b & 0x80000000u) ? ~b : (b | 0x80000000u);
    sk[j] = ((u64)u << 32) | (u32)(~(u32)gj);
  }
  __syncthreads();
  const int i0 = tid * 16;
  if (i0 >= n) return;
  u64 myk[16];
  int cnt[16];
  #pragma unroll
  for (int e = 0; e < 16; ++e) {
    int i = i0 + e;
    u64 key = 0ULL;
    if (i < n) {
      u32 b = __float_as_uint(score[i]);
      u32 u = (b & 0x80000000u) ? ~b : (b | 0x80000000u);
      key = ((u64)u << 32) | (u32)(~(u32)i);
    }
    myk[e] = key; cnt[e] = 0;
  }
  #pragma unroll 4
  for (int j = 0; j < slice; ++j) {
    u64 kj = sk[j];
    #pragma unroll
    for (int e = 0; e < 16; ++e) cnt[e] += (kj > myk[e]) ? 1 : 0;
  }
  #pragma unroll
  for (int e = 0; e < 16; ++e) {
    int i = i0 + e;
    if (i < n) prank[s * n + i] = cnt[e];
  }
}

__global__ void rank_scatter_k(const int* __restrict__ prank, int n, int ns, int k,
                               int* __restrict__ perm, int* __restrict__ inv) {
  int i = blockIdx.x * 256 + threadIdx.x;
  if (i >= n) return;
  int r = 0;
  for (int s = 0; s < ns; ++s) r += prank[s * n + i];
  inv[i] = (r < k) ? r : -1;
  if (r < k) perm[r] = i;
}

// fused matvec2 + log-softmax output, vectorized A loads
__global__ void matvec2_final_k(const void* __restrict__ A, int abf, int n,
                                const float* __restrict__ Zs, const double* __restrict__ rs0,
                                const float* __restrict__ b2, float* __restrict__ out,
                                const int* __restrict__ dtf) {
  const int bf = get_bf(abf, dtf);
  int row = blockIdx.x, tid = threadIdx.x;
  const long base = (long)row * n;
  double s0 = 0.0, s1 = 0.0;
  for (int j4 = tid; j4 < (n >> 2); j4 += 256) {
    const int j = j4 << 2;
    float a0, a1, a2, a3;
    if (bf) {
      ushort4 u = *(const ushort4*)((const u16*)A + base + j);
      a0 = bf2f(u.x); a1 = bf2f(u.y); a2 = bf2f(u.z); a3 = bf2f(u.w);
    } else {
      float4 f = *(const float4*)((const float*)A + base + j);
      a0 = f.x; a1 = f.y; a2 = f.z; a3 = f.w;
    }
    const float4 z01 = *(const float4*)(Zs + 2 * j);
    const float4 z23 = *(const float4*)(Zs + 2 * j + 4);
    s0 += (double)a0 * (double)z01.x; s1 += (double)a0 * (double)z01.y;
    s0 += (double)a1 * (double)z01.z; s1 += (double)a1 * (double)z01.w;
    s0 += (double)a2 * (double)z23.x; s1 += (double)a2 * (double)z23.y;
    s0 += (double)a3 * (double)z23.z; s1 += (double)a3 * (double)z23.w;
  }
  __shared__ double r0[256], r1[256];
  r0[tid] = s0; r1[tid] = s1; __syncthreads();
  for (int st = 128; st > 0; st >>= 1) {
    if (tid < st) { r0[tid] += r0[tid + st]; r1[tid] += r1[tid + st]; }
    __syncthreads();
  }
  if (tid == 0) {
    double y0 = (double)((float)r0[0]);
    double y1 = (double)((float)r1[0]);
    double di = (double)((float)(1.0 / sqrt(rs0[row] + 2.0)));
    double t0 = di * (y0 + 2.0 * (double)Zs[2 * row]) + (double)b2[0];
    double t1 = di * (y1 + 2.0 * (double)Zs[2 * row + 1]) + (double)b2[1];
    double mx = fmax(t0, t1);
    double l = mx + log(exp(t0 - mx) + exp(t1 - mx));
    out[2 * row] = (float)(t0 - l);
    out[2 * row + 1] = (float)(t1 - l);
  }
}

// ---------- host orchestration ----------
extern "C" void kernel_launch(void* const* d_in, const int* in_sizes, int n_in,
                              void* d_out, int out_size, void* d_ws, size_t ws_size,
                              hipStream_t stream) {
  const int N0 = 4096, H = 200;
  const int K1 = 3072, K2 = 1536, K3 = 768;
  const int TK_NS = 64;

  const void* in_x = d_in[0];
  const void* adj  = d_in[1];
  const void* w0 = d_in[2];  const void* b0 = d_in[3];
  const void* w1 = d_in[4];  const void* b1 = d_in[5];
  const void* w2 = d_in[6];  const void* b2 = d_in[7];
  const void* w3 = d_in[8];  const void* b3 = d_in[9];
  const void* p1 = d_in[10]; const void* p2 = d_in[11];
  const void* p3 = d_in[12];
  const void* u0w = d_in[13]; const void* u0b = d_in[14];
  const void* u1w = d_in[15]; const void* u1b = d_in[16];
  const void* u2w = d_in[17]; const void* u2b = d_in[18];

  char* wp = (char*)d_ws;
  auto alloc = [&](size_t bytes) -> void* {
    void* p = (void*)wp;
    wp += (bytes + 255) & ~(size_t)255;
    return p;
  };
  size_t partsBytes = (size_t)300 * 4 * 16384 * 4 + 1024;
  float* parts = (float*)alloc(partsBytes);
  s8*    Agb  = (s8*)alloc((size_t)K1 * N0);   // i8 augment operand (coexists w/ parts)
  u16* Ag3h = (u16*)alloc((size_t)K3 * K2 * 2);
  u16* Ag3l = (u16*)alloc((size_t)K3 * K2 * 2);
  u16* Ah0 = (u16*)alloc((size_t)N0 * N0 * 2);
  u16* Ah1 = (u16*)alloc((size_t)K1 * K1 * 2);
  u16* Ah2 = (u16*)alloc((size_t)K2 * K2 * 2);
  u16* Al2 = (u16*)alloc((size_t)K2 * K2 * 2);
  u16* Ah3 = (u16*)alloc((size_t)K3 * K3 * 2);
  u16* Al3 = (u16*)alloc((size_t)K3 * K3 * 2);
  u16* ZT  = (u16*)alloc((size_t)3 * 208 * N0 * 2);
  float* xs0  = (float*)alloc((size_t)N0 * H * 4);
  float* xs1  = (float*)alloc((size_t)K1 * H * 4);
  float* xs2  = (float*)alloc((size_t)K2 * H * 4);
  float* xcur = (float*)alloc((size_t)N0 * H * 4);
  float* xtmp = (float*)alloc((size_t)N0 * H * 4);
  float* Zbuf = (float*)alloc((size_t)N0 * H * 4);
  float* Xinf = (float*)alloc((size_t)N0 * 3 * 4);
  double* rs0 = (double*)alloc((size_t)N0 * 8);
  double* rs1 = (double*)alloc((size_t)K1 * 8);   // rs1..rs3 + dtflag contiguous, one memset
  double* rs2 = (double*)alloc((size_t)K2 * 8);
  double* rs3 = (double*)alloc((size_t)K3 * 8);
  int* dtflag = (int*)alloc(256);
  float* scores = (float*)alloc((size_t)N0 * 4);
  int* prank = (int*)alloc((size_t)TK_NS * N0 * 4);
  int* perm1 = (int*)alloc((size_t)K1 * 4);
  int* perm2 = (int*)alloc((size_t)K2 * 4);
  int* perm3 = (int*)alloc((size_t)K3 * 4);
  int* inv1 = (int*)alloc((size_t)N0 * 4);
  int* inv2 = (int*)alloc((size_t)K1 * 4);
  int* inv3 = (int*)alloc((size_t)K2 * 4);
  float* w0f = (float*)alloc(3 * H * 4);  float* b0f = (float*)alloc(H * 4);
  float* w1f = (float*)alloc(H * H * 4);  float* b1f = (float*)alloc(H * 4);
  float* w2f = (float*)alloc(H * H * 4);  float* b2f = (float*)alloc(H * 4);
  float* w3f = (float*)alloc(H * H * 4);  float* b3f = (float*)alloc(H * 4);
  float* p1f = (float*)alloc(H * 4);
  float* p2f = (float*)alloc(H * 4);
  float* p3f = (float*)alloc(H * 4);
  float* u0wf = (float*)alloc(H * H * 4); float* u0bf = (float*)alloc(H * 4);
  float* u1wf = (float*)alloc(H * H * 4); float* u1bf = (float*)alloc(H * 4);
  float* u2wf = (float*)alloc(H * 2 * 4); float* u2bf = (float*)alloc(2 * 4);
  (void)in_sizes; (void)n_in; (void)out_size; (void)ws_size; (void)xtmp;

  // zero rs1..rs3 + dtflag in one memset (contiguous, 256B multiples)
  hipMemsetAsync(rs1, 0, (size_t)(K1 + K2 + K3) * 8 + 256, stream);
  detect_k<<<dim3(2048), dim3(256), 0, stream>>>((const u32*)adj, (long)N0 * N0 / 2, dtflag);

  {
    UpBatch ub;
    const void* srcs[19] = {in_x, w0, b0, w1, b1, w2, b2, w3, b3, p1, p2, p3,
                            u0w, u0b, u1w, u1b, u2w, u2b, u2b};
    float* dsts[19] = {Xinf, w0f, b0f, w1f, b1f, w2f, b2f, w3f, b3f, p1f, p2f, p3f,
                       u0wf, u0bf, u1wf, u1bf, u2wf, u2bf, u2bf};
    int ns[19] = {N0 * 3, 3 * H, H, H * H, H, H * H, H, H * H, H, H, H, H,
                  H * H, H, H * H, H, H * 2, 2, 2};
    for (int i = 0; i < 19; ++i) { ub.src[i] = srcs[i]; ub.dst[i] = dsts[i]; ub.n[i] = ns[i]; }
    upcast_batch_k<<<dim3((N0 * 3 + 255) / 256, 19), dim3(256), 0, stream>>>(ub, dtflag);
  }

  a_from_adj_rs_k<<<dim3(N0), dim3(256), 0, stream>>>(adj, dtflag, N0, Ah0, rs0);

  auto gemm64 = [&](const void* A, long lda, int abf, const void* B, long ldb, int bbf,
                    float* C, long ldc, int M, int Nn, int K, const double* rsum, u16* zt,
                    const float* uaPool, const int* uaInv) {
    dim3 g((Nn + 63) / 64, (M + 63) / 64);
    gemm64_f64<<<g, dim3(256), 0, stream>>>(A, lda, abf, B, ldb, bbf, C, ldc, M, Nn, K,
                                            rsum, zt, dtflag, uaPool, uaInv);
  };

  // GCN: out = maybe_relu(dinv .* (A@Zs + 2 Zs) + b); optional fused pooling score.
  auto gcn = [&](const u16* Ah, const u16* Al, int n, int chunks, const double* rs,
                 const float* Xin_, int din, const float* W, const float* bb,
                 float* out, const float* pwf, float* scoreOut,
                 const float* uaPool, const int* uaInv) {
    gemm64(Xin_, din, 0, W, H, 0, Zbuf, H, n, H, din, rs, ZT, uaPool, uaInv);
    if (Al)
      agg_mfma8z<1><<<dim3(n / 128, chunks, 2), dim3(512), 0, stream>>>(
          Ah, Al, ZT, parts, n, (n / 32) / chunks);
    else
      agg_mfma8z<0><<<dim3(n / 128, chunks, 2), dim3(512), 0, stream>>>(
          Ah, nullptr, ZT, parts, n, (n / 32) / chunks);
    reduce_epi_k<<<dim3(n), dim3(256), 0, stream>>>(
        parts, Zbuf, rs, bb, out, n, chunks, 1, pwf, scoreOut);
  };

  auto topk = [&](const float* sc, int n, int k, int* perm, int* inv) {
    rank_part_k<<<dim3(TK_NS), dim3(256), 0, stream>>>(sc, n, TK_NS, prank);
    rank_scatter_k<<<dim3((unsigned)((n + 255) / 256)), dim3(256), 0, stream>>>(
        prank, n, TK_NS, k, perm, inv);
  };

  // ---------------- forward ----------------
  gcn(Ah0, nullptr, N0, 8, rs0, Xinf, 3, w0f, b0f, xs0, p1f, scores, nullptr, nullptr);

  // down 0: i8 SYRK, single-pass 8-wave (dbuf pipeline + direct write + mirror + rowsum)
  topk(scores, N0, K1, perm1, inv1);
  {
    unsigned nbB = (unsigned)(((long)K1 * N0 / 4 + 255) / 256);
    unsigned nbG = (unsigned)(((long)K1 * 50 + 255) / 256);
    bg_i8_k<<<dim3(nbB + nbG), dim3(256), 0, stream>>>(
        Ah0, 1, N0, perm1, K1, Agb, dtflag, xs0, scores, xcur, nbB);
    int nt = K1 / 128;
    int ntri = nt * (nt + 1) / 2;  // 300
    syrk_tri_i8_full<<<dim3(ntri), dim3(512), 0, stream>>>(
        Agb, N0, N0, K1, Ah1, nullptr, rs1);
  }
  gcn(Ah1, nullptr, K1, 8, rs1, xcur, H, w1f, b1f, xs1, p2f, scores, nullptr, nullptr);

  // down 1: i8 SYRK K-split int32 parts (S=8 -> 624 blocks); fused reduce+rowsum
  topk(scores, K1, K2, perm2, inv2);
  {
    unsigned nbB = (unsigned)(((long)K2 * K1 / 4 + 255) / 256);
    unsigned nbG = (unsigned)(((long)K2 * 50 + 255) / 256);
    bg_i8_k<<<dim3(nbB + nbG), dim3(256), 0, stream>>>(
        Ah1, 1, K1, perm2, K2, Agb, dtflag, xs1, scores, xcur, nbB);
    int nt = K2 / 128;
    int ntri = nt * (nt + 1) / 2;  // 78
    syrk_tri_i8_parts<int><<<dim3(ntri, 8), dim3(256), 0, stream>>>(
        Agb, K1, K1 / 8, ntri, (int*)parts);
    reduce_tri_i8_k<int><<<dim3(ntri * 4), dim3(256), 0, stream>>>(
        (const int*)parts, ntri, K2, 8, Ah2, Al2, rs2);
  }
  gcn(Ah2, Al2, K2, 12, rs2, xcur, H, w2f, b2f, xs2, p3f, scores, nullptr, nullptr);

  // down 2: bf16 2-plane K-split triangle (Ah3/Al3 + rowsum in reduce)
  topk(scores, K2, K3, perm3, inv3);
  {
    unsigned nbB = (unsigned)(((long)K3 * K2 / 4 + 255) / 256);
    unsigned nbG = (unsigned)(((long)K3 * 50 + 255) / 256);
    bg_sp_k<<<dim3(nbB + nbG), dim3(256), 0, stream>>>(
        Ah2, Al2, K2, perm3, K3, Ag3h, Ag3l, xs2, scores, xcur, nbB);
    int nt = K3 / 128;
    syrk_tri2_parts<<<dim3(nt * (nt + 1) / 2, 8), dim3(256), 0, stream>>>(
        Ag3h, Ag3l, K2, parts, K3, K2 / 8);
    long nn = (long)K3 * K3;
    reduce_tri_mirror_k<<<dim3((unsigned)(nn / 256)), dim3(256), 0, stream>>>(
        parts, Ah3, Al3, rs3, K3, 8);
  }
  gcn(Ah3, Al3, K3, 24, rs3, xcur, H, w3f, b3f, xcur, nullptr, nullptr, nullptr, nullptr);

  // up 0: j=2  (A = xs2 + upscatter(xcur) fused into the GEMM)
  gcn(Ah2, Al2, K2, 12, rs2, xs2, H, u0wf, u0bf, xcur, nullptr, nullptr, xcur, inv3);

  // up 1: j=1
  gcn(Ah1, nullptr, K1, 8, rs1, xs1, H, u1wf, u1bf, xcur, nullptr, nullptr, xcur, inv2);

  // up 2: j=0 (final, f64; A = xs0 + upscatter(xcur)); matvec reads bf16 Ah0.
  gemm64(xs0, H, 0, u2wf, 2, 0, Zbuf, 2, N0, 2, H, rs0, nullptr, xcur, inv1);
  matvec2_final_k<<<dim3(N0), dim3(256), 0, stream>>>(
      Ah0, 1, N0, Zbuf, rs0, u2bf, (float*)d_out, dtflag);
}